// Round 1
// baseline (5064.360 us; speedup 1.0000x reference)
//
#include <hip/hip_runtime.h>

#define NE_N 50000
#define NP_N 25000
#define E_N 200000
#define DIM 128

// ---------------------------------------------------------------------------
// vec[lt][i] = sum_j W_dst[lt][i][j] * att_dst[lt][j]   (12 blocks x 128 thr)
__global__ __launch_bounds__(128) void precompute_vec_k(
    const float* __restrict__ W_dst, const float* __restrict__ att_dst,
    float* __restrict__ vec) {
  int lt = blockIdx.x;
  int i = threadIdx.x;
  const float* Wd = W_dst + (size_t)lt * DIM * DIM;
  const float* ad = att_dst + lt * DIM;
  float s = 0.f;
#pragma unroll 8
  for (int j = 0; j < DIM; j++) s += Wd[i * DIM + j] * ad[j];
  vec[lt * DIM + i] = s;
}

// ---------------------------------------------------------------------------
// out[i][j] = b0[j] + b1[j]   (n = N*128 elements)
__global__ __launch_bounds__(256) void init_bias_k(
    float* __restrict__ out, const float* __restrict__ b0,
    const float* __restrict__ b1, int n) {
  int idx = blockIdx.x * 256 + threadIdx.x;
  if (idx >= n) return;
  int j = idx & 127;
  out[idx] = b0[j] + b1[j];
}

// ---------------------------------------------------------------------------
// hs = x @ W  [N,128]@[128,128], es = hs @ a_s.
// Block: 256 threads, tile 64 rows x 128 cols; thread = 4 rows x 8 cols.
__global__ __launch_bounds__(256) void gemm_hs_es(
    const float* __restrict__ x, const float* __restrict__ W,
    const float* __restrict__ a_s, float* __restrict__ hs,
    float* __restrict__ es, int N) {
  __shared__ float sW[16][DIM];      // k-chunk of W (8 KB)
  __shared__ float sX[64][17];       // x chunk, padded (4.25 KB)
  const int t = threadIdx.x;
  const int colg = t & 15;           // col group: cols [8*colg, 8*colg+8)
  const int rowg = t >> 4;           // row group 0..15, rows rowg + 16*i
  const int col8 = colg * 8;
  const int row0 = blockIdx.x * 64;

  float acc[4][8];
#pragma unroll
  for (int i = 0; i < 4; i++)
#pragma unroll
    for (int c = 0; c < 8; c++) acc[i][c] = 0.f;

  for (int k0 = 0; k0 < DIM; k0 += 16) {
    // load W[k0:k0+16][:]: 2048 floats, 8/thread
    {
      int kk = t >> 4, cc = (t & 15) * 8;
      *(float4*)&sW[kk][cc]     = *(const float4*)&W[(k0 + kk) * DIM + cc];
      *(float4*)&sW[kk][cc + 4] = *(const float4*)&W[(k0 + kk) * DIM + cc + 4];
    }
    // load x[row0:row0+64][k0:k0+16]: 1024 floats, 4/thread
    {
      int r = t >> 2, kk4 = (t & 3) * 4;
      int gr = row0 + r;
      float4 v = make_float4(0.f, 0.f, 0.f, 0.f);
      if (gr < N) v = *(const float4*)&x[(size_t)gr * DIM + k0 + kk4];
      sX[r][kk4] = v.x; sX[r][kk4 + 1] = v.y;
      sX[r][kk4 + 2] = v.z; sX[r][kk4 + 3] = v.w;
    }
    __syncthreads();
#pragma unroll
    for (int kk = 0; kk < 16; kk++) {
      float4 wa = *(float4*)&sW[kk][col8];
      float4 wb = *(float4*)&sW[kk][col8 + 4];
#pragma unroll
      for (int i = 0; i < 4; i++) {
        float xv = sX[rowg + 16 * i][kk];
        acc[i][0] += xv * wa.x; acc[i][1] += xv * wa.y;
        acc[i][2] += xv * wa.z; acc[i][3] += xv * wa.w;
        acc[i][4] += xv * wb.x; acc[i][5] += xv * wb.y;
        acc[i][6] += xv * wb.z; acc[i][7] += xv * wb.w;
      }
    }
    __syncthreads();
  }

  float4 as0 = *(const float4*)&a_s[col8];
  float4 as1 = *(const float4*)&a_s[col8 + 4];
#pragma unroll
  for (int i = 0; i < 4; i++) {
    int r = row0 + rowg + 16 * i;
    float p = acc[i][0] * as0.x + acc[i][1] * as0.y + acc[i][2] * as0.z +
              acc[i][3] * as0.w + acc[i][4] * as1.x + acc[i][5] * as1.y +
              acc[i][6] * as1.z + acc[i][7] * as1.w;
#pragma unroll
    for (int off = 8; off > 0; off >>= 1) p += __shfl_down(p, off, 16);
    if (r < N) {
      *(float4*)&hs[(size_t)r * DIM + col8] =
          make_float4(acc[i][0], acc[i][1], acc[i][2], acc[i][3]);
      *(float4*)&hs[(size_t)r * DIM + col8 + 4] =
          make_float4(acc[i][4], acc[i][5], acc[i][6], acc[i][7]);
      if (colg == 0) es[r] = p;
    }
  }
}

// ---------------------------------------------------------------------------
// ed[row] = dot(x[row], v)  — one row per 32-lane group
__global__ __launch_bounds__(256) void matvec_ed(
    const float* __restrict__ x, const float* __restrict__ v,
    float* __restrict__ ed, int N) {
  int lane = threadIdx.x & 31;
  int row = (blockIdx.x * 256 + threadIdx.x) >> 5;
  if (row >= N) return;
  float4 xv = *(const float4*)&x[(size_t)row * DIM + lane * 4];
  float4 vv = *(const float4*)&v[lane * 4];
  float p = xv.x * vv.x + xv.y * vv.y + xv.z * vv.z + xv.w * vv.w;
#pragma unroll
  for (int off = 16; off > 0; off >>= 1) p += __shfl_down(p, off, 32);
  if (lane == 0) ed[row] = p;
}

// ---------------------------------------------------------------------------
// logit[e] = relu(es[src]+ed[dst]); m[dst] = max (uint atomics, all >= 0)
__global__ __launch_bounds__(256) void pass_logit_max(
    const float* __restrict__ es, const float* __restrict__ ed,
    const int* __restrict__ src, const int* __restrict__ dst,
    float* __restrict__ logit, float* __restrict__ m, int E) {
  int e = blockIdx.x * 256 + threadIdx.x;
  if (e >= E) return;
  float v = fmaxf(es[src[e]] + ed[dst[e]], 0.f);
  logit[e] = v;
  atomicMax((unsigned int*)&m[dst[e]], __float_as_uint(v));
}

// ---------------------------------------------------------------------------
// w[e] = exp(logit - m[dst]); denom[dst] += w
__global__ __launch_bounds__(256) void pass_w_denom(
    const float* __restrict__ logit, const float* __restrict__ m,
    const int* __restrict__ dst, float* __restrict__ w,
    float* __restrict__ denom, int E) {
  int e = blockIdx.x * 256 + threadIdx.x;
  if (e >= E) return;
  int d = dst[e];
  float wv = expf(logit[e] - m[d]);
  w[e] = wv;
  unsafeAtomicAdd(&denom[d], wv);
}

// ---------------------------------------------------------------------------
// out[dst] += (w/denom[dst]) * hs[src]   — one edge per 32-lane group, float4
__global__ __launch_bounds__(256) void pass_scatter(
    const float* __restrict__ w, const float* __restrict__ denom,
    const float* __restrict__ hs, const int* __restrict__ src,
    const int* __restrict__ dst, float* __restrict__ out, int E) {
  int lane = threadIdx.x & 31;
  int e = (blockIdx.x * 256 + threadIdx.x) >> 5;
  if (e >= E) return;
  int s = src[e], d = dst[e];
  float alpha = w[e] / fmaxf(denom[d], 1e-16f);
  float4 h = *(const float4*)&hs[(size_t)s * DIM + lane * 4];
  float* o = &out[(size_t)d * DIM + lane * 4];
  unsafeAtomicAdd(o + 0, alpha * h.x);
  unsafeAtomicAdd(o + 1, alpha * h.y);
  unsafeAtomicAdd(o + 2, alpha * h.z);
  unsafeAtomicAdd(o + 3, alpha * h.w);
}

// ---------------------------------------------------------------------------
// colsum[j] = sum over all rows of xe and xp (256 blocks x 256 thr)
__global__ __launch_bounds__(256) void colsum_k(
    const float* __restrict__ xe, const float* __restrict__ xp,
    float* __restrict__ colsum) {
  int tid = blockIdx.x * 256 + threadIdx.x;
  const int stride = 256 * 256;  // multiple of 128 -> fixed column per thread
  float s = 0.f;
  for (int idx = tid; idx < NE_N * DIM; idx += stride) s += xe[idx];
  for (int idx = tid; idx < NP_N * DIM; idx += stride) s += xp[idx];
  __shared__ float ls[256];
  ls[threadIdx.x] = s;
  __syncthreads();
  if (threadIdx.x < 128)
    unsafeAtomicAdd(&colsum[threadIdx.x], ls[threadIdx.x] + ls[threadIdx.x + 128]);
}

// ---------------------------------------------------------------------------
__global__ void final_proj(const float* __restrict__ colsum,
                           const float* __restrict__ lin_W,
                           const float* __restrict__ lin_b,
                           float* __restrict__ out) {
  int j = threadIdx.x;
  if (j >= 2) return;
  float s = 0.f;
#pragma unroll 8
  for (int k = 0; k < DIM; k++) s += colsum[k] * lin_W[k * 2 + j];
  out[j] = s / (float)(NE_N + NP_N) + lin_b[j];
}

// ---------------------------------------------------------------------------
extern "C" void kernel_launch(void* const* d_in, const int* in_sizes, int n_in,
                              void* d_out, int out_size, void* d_ws,
                              size_t ws_size, hipStream_t stream) {
  const float* x_elem  = (const float*)d_in[0];
  const float* x_proc  = (const float*)d_in[1];
  const float* W_src   = (const float*)d_in[2];
  const float* W_dst   = (const float*)d_in[3];
  const float* att_src = (const float*)d_in[4];
  const float* att_dst = (const float*)d_in[5];
  const float* bias    = (const float*)d_in[6];
  const float* lin_W   = (const float*)d_in[7];
  const float* lin_b   = (const float*)d_in[8];
  const int* esrc[4] = {(const int*)d_in[9],  (const int*)d_in[11],
                        (const int*)d_in[13], (const int*)d_in[15]};
  const int* edst[4] = {(const int*)d_in[10], (const int*)d_in[12],
                        (const int*)d_in[14], (const int*)d_in[16]};

  float* ws = (float*)d_ws;
  float* xe_a = ws;                         // 6.4M
  float* xe_b = xe_a + NE_N * DIM;          // 6.4M
  float* xp_a = xe_b + NE_N * DIM;          // 3.2M
  float* xp_b = xp_a + NP_N * DIM;          // 3.2M
  float* hs   = xp_b + NP_N * DIM;          // 6.4M
  float* es   = hs + NE_N * DIM;            // 50000
  float* ed   = es + NE_N;                  // 50000
  float* m    = ed + NE_N;                  // 50000
  float* den  = m + NE_N;                   // 50000
  float* lg   = den + NE_N;                 // 200000
  float* wbuf = lg + E_N;                   // 200000
  float* vec  = wbuf + E_N;                 // 1536
  float* csum = vec + 12 * DIM;             // 128

  precompute_vec_k<<<12, 128, 0, stream>>>(W_dst, att_dst, vec);

  const float* cur_e = x_elem;
  const float* cur_p = x_proc;
  float* ebufs[2] = {xe_a, xe_b};
  float* pbufs[2] = {xp_a, xp_b};

  for (int l = 0; l < 3; l++) {
    float* nxt_e = ebufs[l & 1];
    float* nxt_p = pbufs[l & 1];
    init_bias_k<<<(NE_N * DIM + 255) / 256, 256, 0, stream>>>(
        nxt_e, bias + (l * 4 + 0) * DIM, bias + (l * 4 + 3) * DIM, NE_N * DIM);
    init_bias_k<<<(NP_N * DIM + 255) / 256, 256, 0, stream>>>(
        nxt_p, bias + (l * 4 + 1) * DIM, bias + (l * 4 + 2) * DIM, NP_N * DIM);

    for (int t = 0; t < 4; t++) {
      const bool src_is_e = (t == 0 || t == 1);
      const bool dst_is_e = (t == 0 || t == 3);
      const float* xs = src_is_e ? cur_e : cur_p;
      int Ns = src_is_e ? NE_N : NP_N;
      const float* xd = dst_is_e ? cur_e : cur_p;
      int Nd = dst_is_e ? NE_N : NP_N;
      float* outbuf = dst_is_e ? nxt_e : nxt_p;
      int lt = l * 4 + t;

      gemm_hs_es<<<(Ns + 63) / 64, 256, 0, stream>>>(
          xs, W_src + (size_t)lt * DIM * DIM, att_src + lt * DIM, hs, es, Ns);
      matvec_ed<<<(Nd * 32 + 255) / 256, 256, 0, stream>>>(xd, vec + lt * DIM,
                                                           ed, Nd);
      hipMemsetAsync(m, 0, Nd * sizeof(float), stream);
      hipMemsetAsync(den, 0, Nd * sizeof(float), stream);
      pass_logit_max<<<(E_N + 255) / 256, 256, 0, stream>>>(es, ed, esrc[t],
                                                            edst[t], lg, m, E_N);
      pass_w_denom<<<(E_N + 255) / 256, 256, 0, stream>>>(lg, m, edst[t], wbuf,
                                                          den, E_N);
      pass_scatter<<<(E_N * 32 + 255) / 256, 256, 0, stream>>>(
          wbuf, den, hs, esrc[t], edst[t], outbuf, E_N);
    }
    cur_e = nxt_e;
    cur_p = nxt_p;
  }

  hipMemsetAsync(csum, 0, DIM * sizeof(float), stream);
  colsum_k<<<256, 256, 0, stream>>>(cur_e, cur_p, csum);
  final_proj<<<1, 64, 0, stream>>>(csum, lin_W, lin_b, (float*)d_out);
}

// Round 2
// 1271.695 us; speedup vs baseline: 3.9824x; 3.9824x over previous
//
#include <hip/hip_runtime.h>

#define NE_N 50000
#define NP_N 25000
#define E_N 200000
#define DIM 128

// ---------------------------------------------------------------------------
// vec[lt][i] = sum_j W_dst[lt][i][j] * att_dst[lt][j]   (12 blocks x 128 thr)
__global__ __launch_bounds__(128) void precompute_vec_k(
    const float* __restrict__ W_dst, const float* __restrict__ att_dst,
    float* __restrict__ vec) {
  int lt = blockIdx.x;
  int i = threadIdx.x;
  const float* Wd = W_dst + (size_t)lt * DIM * DIM;
  const float* ad = att_dst + lt * DIM;
  float s = 0.f;
#pragma unroll 8
  for (int j = 0; j < DIM; j++) s += Wd[i * DIM + j] * ad[j];
  vec[lt * DIM + i] = s;
}

// ---------------------------------------------------------------------------
// hs = x @ W  [N,128]@[128,128], es = hs @ a_s.
// Block: 256 threads, tile 64 rows x 128 cols; thread = 4 rows x 8 cols.
__global__ __launch_bounds__(256) void gemm_hs_es(
    const float* __restrict__ x, const float* __restrict__ W,
    const float* __restrict__ a_s, float* __restrict__ hs,
    float* __restrict__ es, int N) {
  __shared__ float sW[16][DIM];      // k-chunk of W (8 KB)
  __shared__ float sX[64][17];       // x chunk, padded (4.25 KB)
  const int t = threadIdx.x;
  const int colg = t & 15;           // col group: cols [8*colg, 8*colg+8)
  const int rowg = t >> 4;           // row group 0..15, rows rowg + 16*i
  const int col8 = colg * 8;
  const int row0 = blockIdx.x * 64;

  float acc[4][8];
#pragma unroll
  for (int i = 0; i < 4; i++)
#pragma unroll
    for (int c = 0; c < 8; c++) acc[i][c] = 0.f;

  for (int k0 = 0; k0 < DIM; k0 += 16) {
    {
      int kk = t >> 4, cc = (t & 15) * 8;
      *(float4*)&sW[kk][cc]     = *(const float4*)&W[(k0 + kk) * DIM + cc];
      *(float4*)&sW[kk][cc + 4] = *(const float4*)&W[(k0 + kk) * DIM + cc + 4];
    }
    {
      int r = t >> 2, kk4 = (t & 3) * 4;
      int gr = row0 + r;
      float4 v = make_float4(0.f, 0.f, 0.f, 0.f);
      if (gr < N) v = *(const float4*)&x[(size_t)gr * DIM + k0 + kk4];
      sX[r][kk4] = v.x; sX[r][kk4 + 1] = v.y;
      sX[r][kk4 + 2] = v.z; sX[r][kk4 + 3] = v.w;
    }
    __syncthreads();
#pragma unroll
    for (int kk = 0; kk < 16; kk++) {
      float4 wa = *(float4*)&sW[kk][col8];
      float4 wb = *(float4*)&sW[kk][col8 + 4];
#pragma unroll
      for (int i = 0; i < 4; i++) {
        float xv = sX[rowg + 16 * i][kk];
        acc[i][0] += xv * wa.x; acc[i][1] += xv * wa.y;
        acc[i][2] += xv * wa.z; acc[i][3] += xv * wa.w;
        acc[i][4] += xv * wb.x; acc[i][5] += xv * wb.y;
        acc[i][6] += xv * wb.z; acc[i][7] += xv * wb.w;
      }
    }
    __syncthreads();
  }

  float4 as0 = *(const float4*)&a_s[col8];
  float4 as1 = *(const float4*)&a_s[col8 + 4];
#pragma unroll
  for (int i = 0; i < 4; i++) {
    int r = row0 + rowg + 16 * i;
    float p = acc[i][0] * as0.x + acc[i][1] * as0.y + acc[i][2] * as0.z +
              acc[i][3] * as0.w + acc[i][4] * as1.x + acc[i][5] * as1.y +
              acc[i][6] * as1.z + acc[i][7] * as1.w;
#pragma unroll
    for (int off = 8; off > 0; off >>= 1) p += __shfl_down(p, off, 16);
    if (r < N) {
      *(float4*)&hs[(size_t)r * DIM + col8] =
          make_float4(acc[i][0], acc[i][1], acc[i][2], acc[i][3]);
      *(float4*)&hs[(size_t)r * DIM + col8 + 4] =
          make_float4(acc[i][4], acc[i][5], acc[i][6], acc[i][7]);
      if (colg == 0) es[r] = p;
    }
  }
}

// ---------------------------------------------------------------------------
// ed[row] = dot(x[row], v)  — one row per 32-lane group
__global__ __launch_bounds__(256) void matvec_ed(
    const float* __restrict__ x, const float* __restrict__ v,
    float* __restrict__ ed, int N) {
  int lane = threadIdx.x & 31;
  int row = (blockIdx.x * 256 + threadIdx.x) >> 5;
  if (row >= N) return;
  float4 xv = *(const float4*)&x[(size_t)row * DIM + lane * 4];
  float4 vv = *(const float4*)&v[lane * 4];
  float p = xv.x * vv.x + xv.y * vv.y + xv.z * vv.z + xv.w * vv.w;
#pragma unroll
  for (int off = 16; off > 0; off >>= 1) p += __shfl_down(p, off, 32);
  if (lane == 0) ed[row] = p;
}

// ---------------------------------------------------------------------------
// CSR build: histogram of dst
__global__ __launch_bounds__(256) void hist_k(const int* __restrict__ dst,
                                              int* __restrict__ cnt, int E) {
  int e = blockIdx.x * 256 + threadIdx.x;
  if (e < E) atomicAdd(&cnt[dst[e]], 1);
}

// exclusive scan of cnt[0..n) -> rp[0..n], also copy to cursor. 1 block, 1024 thr.
// cnt may alias cursor (read before write per element).
__global__ __launch_bounds__(1024) void scan_k(const int* __restrict__ cnt,
                                               int* __restrict__ rp,
                                               int* __restrict__ cursor, int n) {
  __shared__ int wsum[16];
  __shared__ int s_total;
  const int tid = threadIdx.x;
  const int lane = tid & 63, wid = tid >> 6;
  int carry = 0;
  for (int base = 0; base < n; base += 1024) {
    int i = base + tid;
    int v = (i < n) ? cnt[i] : 0;
    int sc = v;  // inclusive wave scan
#pragma unroll
    for (int off = 1; off < 64; off <<= 1) {
      int t = __shfl_up(sc, off, 64);
      if (lane >= off) sc += t;
    }
    if (lane == 63) wsum[wid] = sc;
    __syncthreads();
    if (tid == 0) {
      int acc = 0;
#pragma unroll
      for (int w = 0; w < 16; w++) { int t = wsum[w]; wsum[w] = acc; acc += t; }
      s_total = acc;
    }
    __syncthreads();
    int excl = carry + wsum[wid] + sc - v;
    if (i < n) { rp[i] = excl; cursor[i] = excl; }
    carry += s_total;
    __syncthreads();  // protect wsum before next tile
  }
  if (tid == 0) rp[n] = carry;
}

// fill: pos = cursor[dst]++; ssrc[pos] = src
__global__ __launch_bounds__(256) void fill_csr_k(const int* __restrict__ src,
                                                  const int* __restrict__ dst,
                                                  int* __restrict__ cursor,
                                                  int* __restrict__ ssrc, int E) {
  int e = blockIdx.x * 256 + threadIdx.x;
  if (e < E) {
    int pos = atomicAdd(&cursor[dst[e]], 1);
    ssrc[pos] = src[e];
  }
}

// ---------------------------------------------------------------------------
// One 64-lane wave per dst node: softmax over its edge segment + weighted
// feature gather, single write of the 128-float row. accum=0: out = bias0+bias1
// + acc; accum=1: out += acc.
__global__ __launch_bounds__(256) void gat_gather(
    const int* __restrict__ rp, const int* __restrict__ ssrc,
    const float* __restrict__ es, const float* __restrict__ ed,
    const float* __restrict__ hs, const float* __restrict__ b0,
    const float* __restrict__ b1, float* __restrict__ out, int Nd, int accum) {
  const int lane = threadIdx.x & 63;
  const int node = (blockIdx.x * 256 + threadIdx.x) >> 6;
  if (node >= Nd) return;
  const int beg = rp[node], end = rp[node + 1];
  const float edv = ed[node];

  // segment max of relu(es[src]+ed) (>=0; empty segment -> 0, matches ref)
  float mx = 0.f;
  for (int e = beg + lane; e < end; e += 64)
    mx = fmaxf(mx, fmaxf(es[ssrc[e]] + edv, 0.f));
#pragma unroll
  for (int off = 32; off > 0; off >>= 1)
    mx = fmaxf(mx, __shfl_xor(mx, off, 64));

  // denom
  float sm = 0.f;
  for (int e = beg + lane; e < end; e += 64)
    sm += expf(fmaxf(es[ssrc[e]] + edv, 0.f) - mx);
#pragma unroll
  for (int off = 32; off > 0; off >>= 1) sm += __shfl_xor(sm, off, 64);
  const float inv = 1.f / fmaxf(sm, 1e-16f);

  // weighted gather: lane covers dims {lane, lane+64}
  float a0 = 0.f, a1 = 0.f;
  for (int e = beg; e < end; e++) {
    int s = ssrc[e];
    float al = expf(fmaxf(es[s] + edv, 0.f) - mx) * inv;
    a0 += al * hs[(size_t)s * DIM + lane];
    a1 += al * hs[(size_t)s * DIM + 64 + lane];
  }
  size_t o = (size_t)node * DIM;
  if (accum) {
    out[o + lane] += a0;
    out[o + 64 + lane] += a1;
  } else {
    out[o + lane] = b0[lane] + b1[lane] + a0;
    out[o + 64 + lane] = b0[64 + lane] + b1[64 + lane] + a1;
  }
}

// ---------------------------------------------------------------------------
__global__ __launch_bounds__(256) void colsum_k(
    const float* __restrict__ xe, const float* __restrict__ xp,
    float* __restrict__ colsum) {
  int tid = blockIdx.x * 256 + threadIdx.x;
  const int stride = 256 * 256;  // multiple of 128 -> fixed column per thread
  float s = 0.f;
  for (int idx = tid; idx < NE_N * DIM; idx += stride) s += xe[idx];
  for (int idx = tid; idx < NP_N * DIM; idx += stride) s += xp[idx];
  __shared__ float ls[256];
  ls[threadIdx.x] = s;
  __syncthreads();
  if (threadIdx.x < 128)
    unsafeAtomicAdd(&colsum[threadIdx.x], ls[threadIdx.x] + ls[threadIdx.x + 128]);
}

// ---------------------------------------------------------------------------
__global__ void final_proj(const float* __restrict__ colsum,
                           const float* __restrict__ lin_W,
                           const float* __restrict__ lin_b,
                           float* __restrict__ out) {
  int j = threadIdx.x;
  if (j >= 2) return;
  float s = 0.f;
#pragma unroll 8
  for (int k = 0; k < DIM; k++) s += colsum[k] * lin_W[k * 2 + j];
  out[j] = s / (float)(NE_N + NP_N) + lin_b[j];
}

// ---------------------------------------------------------------------------
extern "C" void kernel_launch(void* const* d_in, const int* in_sizes, int n_in,
                              void* d_out, int out_size, void* d_ws,
                              size_t ws_size, hipStream_t stream) {
  const float* x_elem  = (const float*)d_in[0];
  const float* x_proc  = (const float*)d_in[1];
  const float* W_src   = (const float*)d_in[2];
  const float* W_dst   = (const float*)d_in[3];
  const float* att_src = (const float*)d_in[4];
  const float* att_dst = (const float*)d_in[5];
  const float* bias    = (const float*)d_in[6];
  const float* lin_W   = (const float*)d_in[7];
  const float* lin_b   = (const float*)d_in[8];
  const int* esrc[4] = {(const int*)d_in[9],  (const int*)d_in[11],
                        (const int*)d_in[13], (const int*)d_in[15]};
  const int* edst[4] = {(const int*)d_in[10], (const int*)d_in[12],
                        (const int*)d_in[14], (const int*)d_in[16]};
  // dst-node counts per type
  const int Nd_t[4] = {NE_N, NP_N, NP_N, NE_N};
  const int Ns_t[4] = {NE_N, NE_N, NP_N, NP_N};

  float* ws = (float*)d_ws;
  float* xe_a = ws;                         // 6.4M
  float* xe_b = xe_a + NE_N * DIM;          // 6.4M
  float* xp_a = xe_b + NE_N * DIM;          // 3.2M
  float* xp_b = xp_a + NP_N * DIM;          // 3.2M
  float* hs   = xp_b + NP_N * DIM;          // 6.4M (reused across types)
  float* es   = hs + NE_N * DIM;            // 50000
  float* ed   = es + NE_N;                  // 50000
  float* vec  = ed + NE_N;                  // 1536
  float* csum = vec + 12 * DIM;             // 128
  int* ib = (int*)(csum + DIM);
  int* rp[4], *cursor[4], *ssrc[4];
  for (int t = 0; t < 4; t++) {
    rp[t] = ib;          ib += NE_N + 1;
    cursor[t] = ib;      ib += NE_N + 1;
    ssrc[t] = ib;        ib += E_N;
  }

  // ---- one-time per call: CSR build for 4 edge types + vec precompute ----
  precompute_vec_k<<<12, 128, 0, stream>>>(W_dst, att_dst, vec);
  for (int t = 0; t < 4; t++) {
    hipMemsetAsync(cursor[t], 0, (Nd_t[t]) * sizeof(int), stream);
    hist_k<<<(E_N + 255) / 256, 256, 0, stream>>>(edst[t], cursor[t], E_N);
    scan_k<<<1, 1024, 0, stream>>>(cursor[t], rp[t], cursor[t], Nd_t[t]);
    fill_csr_k<<<(E_N + 255) / 256, 256, 0, stream>>>(esrc[t], edst[t],
                                                      cursor[t], ssrc[t], E_N);
  }

  const float* cur_e = x_elem;
  const float* cur_p = x_proc;
  float* ebufs[2] = {xe_a, xe_b};
  float* pbufs[2] = {xp_a, xp_b};

  for (int l = 0; l < 3; l++) {
    float* nxt_e = ebufs[l & 1];
    float* nxt_p = pbufs[l & 1];
    // order: t0 (dst e, store), t1 (dst p, store), t2 (dst p, accum),
    //        t3 (dst e, accum)
    const int order[4] = {0, 1, 2, 3};
    for (int ti = 0; ti < 4; ti++) {
      int t = order[ti];
      const bool src_is_e = (t == 0 || t == 1);
      const bool dst_is_e = (t == 0 || t == 3);
      const float* xs = src_is_e ? cur_e : cur_p;
      const float* xd = dst_is_e ? cur_e : cur_p;
      int Ns = Ns_t[t], Nd = Nd_t[t];
      float* outbuf = dst_is_e ? nxt_e : nxt_p;
      int accum = (t >= 2) ? 1 : 0;
      int lt = l * 4 + t;
      // bias pair for store mode: dst e -> b[l,0]+b[l,3]; dst p -> b[l,1]+b[l,2]
      const float* b0 = bias + (l * 4 + (dst_is_e ? 0 : 1)) * DIM;
      const float* b1 = bias + (l * 4 + (dst_is_e ? 3 : 2)) * DIM;

      gemm_hs_es<<<(Ns + 63) / 64, 256, 0, stream>>>(
          xs, W_src + (size_t)lt * DIM * DIM, att_src + lt * DIM, hs, es, Ns);
      matvec_ed<<<(Nd * 32 + 255) / 256, 256, 0, stream>>>(xd, vec + lt * DIM,
                                                           ed, Nd);
      gat_gather<<<(Nd * 64 + 255) / 256, 256, 0, stream>>>(
          rp[t], ssrc[t], es, ed, hs, b0, b1, outbuf, Nd, accum);
    }
    cur_e = nxt_e;
    cur_p = nxt_p;
  }

  hipMemsetAsync(csum, 0, DIM * sizeof(float), stream);
  colsum_k<<<256, 256, 0, stream>>>(cur_e, cur_p, csum);
  final_proj<<<1, 64, 0, stream>>>(csum, lin_W, lin_b, (float*)d_out);
}

// Round 3
// 897.139 us; speedup vs baseline: 5.6450x; 1.4175x over previous
//
#include <hip/hip_runtime.h>

#define NE_N 50000
#define NP_N 25000
#define E_N 200000
#define DIM 128

typedef __attribute__((ext_vector_type(8))) short short8;
typedef __attribute__((ext_vector_type(4))) float f32x4;

static __device__ __forceinline__ ushort f2bf(float f) {
  unsigned x = __float_as_uint(f);
  return (ushort)((x + 0x7fffu + ((x >> 16) & 1u)) >> 16);  // RNE
}
static __device__ __forceinline__ float bf2f(ushort u) {
  return __uint_as_float(((unsigned)u) << 16);
}

// ---------------------------------------------------------------------------
// W_src [12][128][128] fp32 -> WbT [12][n][k] bf16 (transposed per matrix)
__global__ __launch_bounds__(256) void conv_w_k(const float* __restrict__ W,
                                                ushort* __restrict__ WbT) {
  int lt = blockIdx.x;
  const float* src = W + (size_t)lt * DIM * DIM;
  ushort* dst = WbT + (size_t)lt * DIM * DIM;
  for (int i = threadIdx.x; i < DIM * DIM; i += 256) {
    int k = i >> 7, n = i & 127;
    dst[n * DIM + k] = f2bf(src[i]);
  }
}

// fp32 [n4*4] -> bf16
__global__ __launch_bounds__(256) void conv_x_k(const float* __restrict__ x,
                                                ushort* __restrict__ xb, int n4) {
  int i = blockIdx.x * 256 + threadIdx.x;
  if (i >= n4) return;
  float4 v = *(const float4*)&x[i * 4];
  ushort4 o;
  o.x = f2bf(v.x); o.y = f2bf(v.y); o.z = f2bf(v.z); o.w = f2bf(v.w);
  *(ushort4*)&xb[i * 4] = o;
}

// ---------------------------------------------------------------------------
// vec[lt][i] = sum_j W_dst[lt][i][j] * att_dst[lt][j]  (fp32, full precision)
__global__ __launch_bounds__(128) void precompute_vec_k(
    const float* __restrict__ W_dst, const float* __restrict__ att_dst,
    float* __restrict__ vec) {
  int lt = blockIdx.x;
  int i = threadIdx.x;
  const float* Wd = W_dst + (size_t)lt * DIM * DIM;
  const float* ad = att_dst + lt * DIM;
  float s = 0.f;
#pragma unroll 8
  for (int j = 0; j < DIM; j++) s += Wd[i * DIM + j] * ad[j];
  vec[lt * DIM + i] = s;
}

// ---------------------------------------------------------------------------
// CSR build
__global__ __launch_bounds__(256) void hist_k(const int* __restrict__ dst,
                                              int* __restrict__ cnt, int E) {
  int e = blockIdx.x * 256 + threadIdx.x;
  if (e < E) atomicAdd(&cnt[dst[e]], 1);
}

// phase A: per-1024-block sums. grid (49, 4)
__global__ __launch_bounds__(256) void scanA_k(
    const int* __restrict__ c0, const int* __restrict__ c1,
    const int* __restrict__ c2, const int* __restrict__ c3,
    int* __restrict__ part) {
  int ty = blockIdx.y;
  const int* cnt = ty == 0 ? c0 : ty == 1 ? c1 : ty == 2 ? c2 : c3;
  int n = (ty == 0 || ty == 3) ? NE_N : NP_N;
  int nblk = (n + 1023) >> 10;
  if ((int)blockIdx.x >= nblk) return;
  int base = blockIdx.x * 1024 + threadIdx.x * 4;
  int s = 0;
#pragma unroll
  for (int j = 0; j < 4; j++) s += (base + j < n) ? cnt[base + j] : 0;
  int lane = threadIdx.x & 63, wid = threadIdx.x >> 6;
#pragma unroll
  for (int off = 32; off > 0; off >>= 1) s += __shfl_xor(s, off, 64);
  __shared__ int ws4[4];
  if (lane == 0) ws4[wid] = s;
  __syncthreads();
  if (threadIdx.x == 0)
    part[ty * 64 + blockIdx.x] = ws4[0] + ws4[1] + ws4[2] + ws4[3];
}

// phase B: scan partials (<=49/type), 1 block, wave w = type w
__global__ __launch_bounds__(256) void scanB_k(
    const int* __restrict__ part, int* __restrict__ part_excl,
    int* __restrict__ r0, int* __restrict__ r1, int* __restrict__ r2,
    int* __restrict__ r3) {
  int ty = threadIdx.x >> 6, lane = threadIdx.x & 63;
  int n = (ty == 0 || ty == 3) ? NE_N : NP_N;
  int nblk = (n + 1023) >> 10;
  int v = (lane < nblk) ? part[ty * 64 + lane] : 0;
  int sc = v;
#pragma unroll
  for (int off = 1; off < 64; off <<= 1) {
    int t = __shfl_up(sc, off, 64);
    if (lane >= off) sc += t;
  }
  if (lane < nblk) part_excl[ty * 64 + lane] = sc - v;
  if (lane == nblk - 1) {
    int* rp = ty == 0 ? r0 : ty == 1 ? r1 : ty == 2 ? r2 : r3;
    rp[n] = sc;  // total
  }
}

// phase C: write exclusive scan to rp + cursor. grid (49, 4)
__global__ __launch_bounds__(256) void scanC_k(
    const int* __restrict__ c0, const int* __restrict__ c1,
    const int* __restrict__ c2, const int* __restrict__ c3,
    int* __restrict__ r0, int* __restrict__ r1, int* __restrict__ r2,
    int* __restrict__ r3, int* __restrict__ u0, int* __restrict__ u1,
    int* __restrict__ u2, int* __restrict__ u3,
    const int* __restrict__ part_excl) {
  int ty = blockIdx.y;
  const int* cnt = ty == 0 ? c0 : ty == 1 ? c1 : ty == 2 ? c2 : c3;
  int* rp = ty == 0 ? r0 : ty == 1 ? r1 : ty == 2 ? r2 : r3;
  int* cur = ty == 0 ? u0 : ty == 1 ? u1 : ty == 2 ? u2 : u3;
  int n = (ty == 0 || ty == 3) ? NE_N : NP_N;
  int nblk = (n + 1023) >> 10;
  if ((int)blockIdx.x >= nblk) return;
  int base = blockIdx.x * 1024 + threadIdx.x * 4;
  int v[4];
#pragma unroll
  for (int j = 0; j < 4; j++) v[j] = (base + j < n) ? cnt[base + j] : 0;
  int s = v[0] + v[1] + v[2] + v[3];
  int lane = threadIdx.x & 63, wid = threadIdx.x >> 6;
  int sc = s;
#pragma unroll
  for (int off = 1; off < 64; off <<= 1) {
    int t = __shfl_up(sc, off, 64);
    if (lane >= off) sc += t;
  }
  __shared__ int ws4[4];
  if (lane == 63) ws4[wid] = sc;
  __syncthreads();
  int wbase = 0;
  for (int w = 0; w < wid; w++) wbase += ws4[w];
  int p = part_excl[ty * 64 + blockIdx.x] + wbase + sc - s;
#pragma unroll
  for (int j = 0; j < 4; j++) {
    if (base + j < n) { rp[base + j] = p; cur[base + j] = p; }
    p += v[j];
  }
}

__global__ __launch_bounds__(256) void fill_csr_k(const int* __restrict__ src,
                                                  const int* __restrict__ dst,
                                                  int* __restrict__ cursor,
                                                  int* __restrict__ ssrc, int E) {
  int e = blockIdx.x * 256 + threadIdx.x;
  if (e < E) {
    int pos = atomicAdd(&cursor[dst[e]], 1);
    ssrc[pos] = src[e];
  }
}

// ---------------------------------------------------------------------------
// MFMA GEMM: hs_bf16 = xb @ W  ([N,128]@[128,128]) + es = hs @ a_s (fp32).
// WbT is W transposed ([n][k]) so both A and B frags are contiguous 16B loads.
// Block 256 = 4 waves; wave w: rows [blk*64 + w*16, +16), all 128 cols.
__global__ __launch_bounds__(256) void gemm_mfma(
    const ushort* __restrict__ xb, const ushort* __restrict__ WbT,
    const float* __restrict__ a_s, ushort* __restrict__ hs,
    float* __restrict__ es, int N) {
  const int wave = threadIdx.x >> 6;
  const int lane = threadIdx.x & 63;
  const int m = lane & 15, quad = lane >> 4;
  const int row0 = blockIdx.x * 64 + wave * 16;
  if (row0 >= N) return;
  int rowA = row0 + m;
  if (rowA >= N) rowA = N - 1;  // clamp loads; stores guarded

  f32x4 acc[8];
#pragma unroll
  for (int f = 0; f < 8; f++) acc[f] = (f32x4){0.f, 0.f, 0.f, 0.f};

  const short8* ap = (const short8*)(xb + (size_t)rowA * DIM + quad * 8);
#pragma unroll
  for (int k0 = 0; k0 < 4; k0++) {
    short8 a = ap[k0 * 4];  // xb[rowA][k0*32 + quad*8 .. +7]
#pragma unroll
    for (int f = 0; f < 8; f++) {
      short8 b = *(const short8*)(WbT + (size_t)(f * 16 + m) * DIM + k0 * 32 +
                                  quad * 8);
      acc[f] = __builtin_amdgcn_mfma_f32_16x16x32_bf16(a, b, acc[f], 0, 0, 0);
    }
  }

  // es epilogue: lane holds C[row=quad*4+reg][col=f*16+m]
  float asv[8];
#pragma unroll
  for (int f = 0; f < 8; f++) asv[f] = a_s[f * 16 + m];
  float ep[4];
#pragma unroll
  for (int r = 0; r < 4; r++) {
    float p = 0.f;
#pragma unroll
    for (int f = 0; f < 8; f++) p += acc[f][r] * asv[f];
#pragma unroll
    for (int off = 1; off < 16; off <<= 1) p += __shfl_xor(p, off, 16);
    ep[r] = p;
  }
  if (m == 0) {
#pragma unroll
    for (int r = 0; r < 4; r++) {
      int rr = row0 + quad * 4 + r;
      if (rr < N) es[rr] = ep[r];
    }
  }

  // hs store (bf16): pack col pairs via lane^1 exchange, even-m lanes store
#pragma unroll
  for (int f = 0; f < 8; f++) {
#pragma unroll
    for (int r = 0; r < 4; r++) {
      int rr = row0 + quad * 4 + r;
      ushort mine = f2bf(acc[f][r]);
      ushort other = (ushort)__shfl_xor((int)mine, 1, 64);
      if (((m & 1) == 0) && rr < N) {
        ushort2 pk; pk.x = mine; pk.y = other;
        *(ushort2*)&hs[(size_t)rr * DIM + f * 16 + m] = pk;
      }
    }
  }
}

// ---------------------------------------------------------------------------
// ed0[r] = x[r]·v0, ed1[r] = x[r]·v1 (x bf16) — one row per 32 lanes
__global__ __launch_bounds__(256) void matvec2_ed(
    const ushort* __restrict__ xb, const float* __restrict__ v0,
    const float* __restrict__ v1, float* __restrict__ ed0,
    float* __restrict__ ed1, int N) {
  int lane = threadIdx.x & 31;
  int row = (blockIdx.x * 256 + threadIdx.x) >> 5;
  if (row >= N) return;
  ushort4 h = *(const ushort4*)&xb[(size_t)row * DIM + lane * 4];
  float4 xv = make_float4(bf2f(h.x), bf2f(h.y), bf2f(h.z), bf2f(h.w));
  float4 a = *(const float4*)&v0[lane * 4];
  float4 b = *(const float4*)&v1[lane * 4];
  float p0 = xv.x * a.x + xv.y * a.y + xv.z * a.z + xv.w * a.w;
  float p1 = xv.x * b.x + xv.y * b.y + xv.z * b.z + xv.w * b.w;
#pragma unroll
  for (int off = 16; off > 0; off >>= 1) {
    p0 += __shfl_down(p0, off, 32);
    p1 += __shfl_down(p1, off, 32);
  }
  if (lane == 0) { ed0[row] = p0; ed1[row] = p1; }
}

// ---------------------------------------------------------------------------
// Fused dual-type gather: out[node] = b0 + b1 + gatA(node) + gatB(node).
// One 64-lane wave per node; lane covers dims {2*lane, 2*lane+1}. hs is bf16.
__global__ __launch_bounds__(256) void gat_gather2(
    const int* __restrict__ rpA, const int* __restrict__ srcA,
    const float* __restrict__ esA, const float* __restrict__ edA,
    const ushort* __restrict__ hsA, const int* __restrict__ rpB,
    const int* __restrict__ srcB, const float* __restrict__ esB,
    const float* __restrict__ edB, const ushort* __restrict__ hsB,
    const float* __restrict__ b0, const float* __restrict__ b1,
    ushort* __restrict__ outb, int Nd) {
  const int lane = threadIdx.x & 63;
  const int node = (blockIdx.x * 256 + threadIdx.x) >> 6;
  if (node >= Nd) return;

  float a0, a1;
  {
    float2 bb0 = *(const float2*)&b0[2 * lane];
    float2 bb1 = *(const float2*)&b1[2 * lane];
    a0 = bb0.x + bb1.x;
    a1 = bb0.y + bb1.y;
  }

#pragma unroll
  for (int half = 0; half < 2; half++) {
    const int* rp = half ? rpB : rpA;
    const int* ss = half ? srcB : srcA;
    const float* es = half ? esB : esA;
    const float* ed = half ? edB : edA;
    const ushort* hs = half ? hsB : hsA;
    const int beg = rp[node], end = rp[node + 1];
    const float edv = ed[node];

    float mx = 0.f;
    for (int e = beg + lane; e < end; e += 64)
      mx = fmaxf(mx, fmaxf(es[ss[e]] + edv, 0.f));
#pragma unroll
    for (int off = 32; off > 0; off >>= 1)
      mx = fmaxf(mx, __shfl_xor(mx, off, 64));

    float sm = 0.f;
    for (int e = beg + lane; e < end; e += 64)
      sm += __expf(fmaxf(es[ss[e]] + edv, 0.f) - mx);
#pragma unroll
    for (int off = 32; off > 0; off >>= 1) sm += __shfl_xor(sm, off, 64);
    const float inv = 1.f / fmaxf(sm, 1e-16f);

    for (int e = beg; e < end; e++) {
      int s = ss[e];
      float al = __expf(fmaxf(es[s] + edv, 0.f) - mx) * inv;
      ushort2 h2 = *(const ushort2*)&hs[(size_t)s * DIM + 2 * lane];
      a0 += al * bf2f(h2.x);
      a1 += al * bf2f(h2.y);
    }
  }

  ushort2 o; o.x = f2bf(a0); o.y = f2bf(a1);
  *(ushort2*)&outb[(size_t)node * DIM + 2 * lane] = o;
}

// ---------------------------------------------------------------------------
__global__ __launch_bounds__(256) void colsum_k(
    const ushort* __restrict__ xe, const ushort* __restrict__ xp,
    float* __restrict__ colsum) {
  int tid = blockIdx.x * 256 + threadIdx.x;
  const int stride = 256 * 256;  // multiple of 128 -> fixed column per thread
  float s = 0.f;
  for (int idx = tid; idx < NE_N * DIM; idx += stride) s += bf2f(xe[idx]);
  for (int idx = tid; idx < NP_N * DIM; idx += stride) s += bf2f(xp[idx]);
  __shared__ float ls[256];
  ls[threadIdx.x] = s;
  __syncthreads();
  if (threadIdx.x < 128)
    unsafeAtomicAdd(&colsum[threadIdx.x], ls[threadIdx.x] + ls[threadIdx.x + 128]);
}

// ---------------------------------------------------------------------------
__global__ void final_proj(const float* __restrict__ colsum,
                           const float* __restrict__ lin_W,
                           const float* __restrict__ lin_b,
                           float* __restrict__ out) {
  int j = threadIdx.x;
  if (j >= 2) return;
  float s = 0.f;
#pragma unroll 8
  for (int k = 0; k < DIM; k++) s += colsum[k] * lin_W[k * 2 + j];
  out[j] = s / (float)(NE_N + NP_N) + lin_b[j];
}

// ---------------------------------------------------------------------------
extern "C" void kernel_launch(void* const* d_in, const int* in_sizes, int n_in,
                              void* d_out, int out_size, void* d_ws,
                              size_t ws_size, hipStream_t stream) {
  const float* x_elem  = (const float*)d_in[0];
  const float* x_proc  = (const float*)d_in[1];
  const float* W_src   = (const float*)d_in[2];
  const float* W_dst   = (const float*)d_in[3];
  const float* att_src = (const float*)d_in[4];
  const float* att_dst = (const float*)d_in[5];
  const float* bias    = (const float*)d_in[6];
  const float* lin_W   = (const float*)d_in[7];
  const float* lin_b   = (const float*)d_in[8];
  const int* esrc[4] = {(const int*)d_in[9],  (const int*)d_in[11],
                        (const int*)d_in[13], (const int*)d_in[15]};
  const int* edst[4] = {(const int*)d_in[10], (const int*)d_in[12],
                        (const int*)d_in[14], (const int*)d_in[16]};
  const int Nd_t[4] = {NE_N, NP_N, NP_N, NE_N};

  // ---- workspace carve-up (bytes) ----
  char* p = (char*)d_ws;
  ushort* xe_bf[2]; ushort* xp_bf[2];
  xe_bf[0] = (ushort*)p; p += (size_t)NE_N * DIM * 2;
  xe_bf[1] = (ushort*)p; p += (size_t)NE_N * DIM * 2;
  xp_bf[0] = (ushort*)p; p += (size_t)NP_N * DIM * 2;
  xp_bf[1] = (ushort*)p; p += (size_t)NP_N * DIM * 2;
  ushort* hsA = (ushort*)p; p += (size_t)NE_N * DIM * 2;  // e-src hs
  ushort* hsB = (ushort*)p; p += (size_t)NP_N * DIM * 2;  // p-src hs
  ushort* WbT = (ushort*)p; p += (size_t)12 * DIM * DIM * 2;
  float* esA = (float*)p; p += NE_N * 4;
  float* esB = (float*)p; p += NE_N * 4;
  float* edA = (float*)p; p += NE_N * 4;
  float* edB = (float*)p; p += NE_N * 4;
  float* vec = (float*)p; p += 12 * DIM * 4;
  float* csum = (float*)p; p += DIM * 4;
  int* part = (int*)p; p += 4 * 64 * 4;
  int* part_excl = (int*)p; p += 4 * 64 * 4;
  int* rp[4]; int* cursor[4]; int* ssrc[4];
  for (int t = 0; t < 4; t++) {
    rp[t] = (int*)p;     p += (NE_N + 4) * 4;
    cursor[t] = (int*)p; p += (NE_N + 4) * 4;
    ssrc[t] = (int*)p;   p += (size_t)E_N * 4;
  }

  // ---- setup: conversions, vec, CSR ----
  conv_w_k<<<12, 256, 0, stream>>>(W_src, WbT);
  conv_x_k<<<(NE_N * DIM / 4 + 255) / 256, 256, 0, stream>>>(x_elem, xe_bf[0],
                                                             NE_N * DIM / 4);
  conv_x_k<<<(NP_N * DIM / 4 + 255) / 256, 256, 0, stream>>>(x_proc, xp_bf[0],
                                                             NP_N * DIM / 4);
  precompute_vec_k<<<12, 128, 0, stream>>>(W_dst, att_dst, vec);

  for (int t = 0; t < 4; t++) {
    hipMemsetAsync(cursor[t], 0, Nd_t[t] * sizeof(int), stream);
    hist_k<<<(E_N + 255) / 256, 256, 0, stream>>>(edst[t], cursor[t], E_N);
  }
  scanA_k<<<dim3(49, 4), 256, 0, stream>>>(cursor[0], cursor[1], cursor[2],
                                           cursor[3], part);
  scanB_k<<<1, 256, 0, stream>>>(part, part_excl, rp[0], rp[1], rp[2], rp[3]);
  scanC_k<<<dim3(49, 4), 256, 0, stream>>>(cursor[0], cursor[1], cursor[2],
                                           cursor[3], rp[0], rp[1], rp[2],
                                           rp[3], cursor[0], cursor[1],
                                           cursor[2], cursor[3], part_excl);
  for (int t = 0; t < 4; t++)
    fill_csr_k<<<(E_N + 255) / 256, 256, 0, stream>>>(esrc[t], edst[t],
                                                      cursor[t], ssrc[t], E_N);

  // ---- layers ----
  int c = 0;
  for (int l = 0; l < 3; l++) {
    int l0 = l * 4 + 0, l1 = l * 4 + 1, l2 = l * 4 + 2, l3 = l * 4 + 3;
    // e-dst: ee (A, e-src) + pe (B, p-src)
    gemm_mfma<<<(NE_N + 63) / 64, 256, 0, stream>>>(
        xe_bf[c], WbT + (size_t)l0 * DIM * DIM, att_src + l0 * DIM, hsA, esA,
        NE_N);
    gemm_mfma<<<(NP_N + 63) / 64, 256, 0, stream>>>(
        xp_bf[c], WbT + (size_t)l3 * DIM * DIM, att_src + l3 * DIM, hsB, esB,
        NP_N);
    matvec2_ed<<<(NE_N * 32 + 255) / 256, 256, 0, stream>>>(
        xe_bf[c], vec + l0 * DIM, vec + l3 * DIM, edA, edB, NE_N);
    gat_gather2<<<(NE_N * 64 + 255) / 256, 256, 0, stream>>>(
        rp[0], ssrc[0], esA, edA, hsA, rp[3], ssrc[3], esB, edB, hsB,
        bias + l0 * DIM, bias + l3 * DIM, xe_bf[1 - c], NE_N);
    // p-dst: ep (A, e-src) + pp (B, p-src)
    gemm_mfma<<<(NE_N + 63) / 64, 256, 0, stream>>>(
        xe_bf[c], WbT + (size_t)l1 * DIM * DIM, att_src + l1 * DIM, hsA, esA,
        NE_N);
    gemm_mfma<<<(NP_N + 63) / 64, 256, 0, stream>>>(
        xp_bf[c], WbT + (size_t)l2 * DIM * DIM, att_src + l2 * DIM, hsB, esB,
        NP_N);
    matvec2_ed<<<(NP_N * 32 + 255) / 256, 256, 0, stream>>>(
        xp_bf[c], vec + l1 * DIM, vec + l2 * DIM, edA, edB, NP_N);
    gat_gather2<<<(NP_N * 64 + 255) / 256, 256, 0, stream>>>(
        rp[1], ssrc[1], esA, edA, hsA, rp[2], ssrc[2], esB, edB, hsB,
        bias + l1 * DIM, bias + l2 * DIM, xp_bf[1 - c], NP_N);
    c = 1 - c;
  }

  hipMemsetAsync(csum, 0, DIM * sizeof(float), stream);
  colsum_k<<<256, 256, 0, stream>>>(xe_bf[c], xp_bf[c], csum);
  final_proj<<<1, 64, 0, stream>>>(csum, lin_W, lin_b, (float*)d_out);
}

// Round 4
// 737.788 us; speedup vs baseline: 6.8642x; 1.2160x over previous
//
#include <hip/hip_runtime.h>

#define NE_N 50000
#define NP_N 25000
#define E_N 200000
#define DIM 128

typedef __attribute__((ext_vector_type(8))) short short8;
typedef __attribute__((ext_vector_type(8))) ushort ushort8;
typedef __attribute__((ext_vector_type(4))) float f32x4;

static __device__ __forceinline__ ushort f2bf(float f) {
  unsigned x = __float_as_uint(f);
  return (ushort)((x + 0x7fffu + ((x >> 16) & 1u)) >> 16);  // RNE
}
static __device__ __forceinline__ float bf2f(ushort u) {
  return __uint_as_float(((unsigned)u) << 16);
}

// ---------------------------------------------------------------------------
// W_src [12][128][128] fp32 -> WbT [12][n][k] bf16 (transposed per matrix)
__global__ __launch_bounds__(256) void conv_w_k(const float* __restrict__ W,
                                                ushort* __restrict__ WbT) {
  int lt = blockIdx.x;
  const float* src = W + (size_t)lt * DIM * DIM;
  ushort* dst = WbT + (size_t)lt * DIM * DIM;
  for (int i = threadIdx.x; i < DIM * DIM; i += 256) {
    int k = i >> 7, n = i & 127;
    dst[n * DIM + k] = f2bf(src[i]);
  }
}

// fp32 [n4*4] -> bf16
__global__ __launch_bounds__(256) void conv_x_k(const float* __restrict__ x,
                                                ushort* __restrict__ xb, int n4) {
  int i = blockIdx.x * 256 + threadIdx.x;
  if (i >= n4) return;
  float4 v = *(const float4*)&x[i * 4];
  ushort4 o;
  o.x = f2bf(v.x); o.y = f2bf(v.y); o.z = f2bf(v.z); o.w = f2bf(v.w);
  *(ushort4*)&xb[i * 4] = o;
}

// ---------------------------------------------------------------------------
// vec[lt][i] = sum_j W_dst[lt][i][j] * att_dst[lt][j]  (fp32, full precision)
__global__ __launch_bounds__(128) void precompute_vec_k(
    const float* __restrict__ W_dst, const float* __restrict__ att_dst,
    float* __restrict__ vec) {
  int lt = blockIdx.x;
  int i = threadIdx.x;
  const float* Wd = W_dst + (size_t)lt * DIM * DIM;
  const float* ad = att_dst + lt * DIM;
  float s = 0.f;
#pragma unroll 8
  for (int j = 0; j < DIM; j++) s += Wd[i * DIM + j] * ad[j];
  vec[lt * DIM + i] = s;
}

// ---------------------------------------------------------------------------
// CSR build: fused histogram over 4 edge types (grid.y = type)
__global__ __launch_bounds__(256) void hist4_k(
    const int* __restrict__ d0, const int* __restrict__ d1,
    const int* __restrict__ d2, const int* __restrict__ d3,
    int* __restrict__ c0, int* __restrict__ c1, int* __restrict__ c2,
    int* __restrict__ c3) {
  int ty = blockIdx.y;
  const int* dst = ty == 0 ? d0 : ty == 1 ? d1 : ty == 2 ? d2 : d3;
  int* cnt = ty == 0 ? c0 : ty == 1 ? c1 : ty == 2 ? c2 : c3;
  int e = blockIdx.x * 256 + threadIdx.x;
  if (e < E_N) atomicAdd(&cnt[dst[e]], 1);
}

// phase A: per-1024-block sums. grid (49, 4)
__global__ __launch_bounds__(256) void scanA_k(
    const int* __restrict__ c0, const int* __restrict__ c1,
    const int* __restrict__ c2, const int* __restrict__ c3,
    int* __restrict__ part) {
  int ty = blockIdx.y;
  const int* cnt = ty == 0 ? c0 : ty == 1 ? c1 : ty == 2 ? c2 : c3;
  int n = (ty == 0 || ty == 3) ? NE_N : NP_N;
  int nblk = (n + 1023) >> 10;
  if ((int)blockIdx.x >= nblk) return;
  int base = blockIdx.x * 1024 + threadIdx.x * 4;
  int s = 0;
#pragma unroll
  for (int j = 0; j < 4; j++) s += (base + j < n) ? cnt[base + j] : 0;
  int lane = threadIdx.x & 63, wid = threadIdx.x >> 6;
#pragma unroll
  for (int off = 32; off > 0; off >>= 1) s += __shfl_xor(s, off, 64);
  __shared__ int ws4[4];
  if (lane == 0) ws4[wid] = s;
  __syncthreads();
  if (threadIdx.x == 0)
    part[ty * 64 + blockIdx.x] = ws4[0] + ws4[1] + ws4[2] + ws4[3];
}

// phase B: scan partials (<=49/type), 1 block, wave w = type w
__global__ __launch_bounds__(256) void scanB_k(
    const int* __restrict__ part, int* __restrict__ part_excl,
    int* __restrict__ r0, int* __restrict__ r1, int* __restrict__ r2,
    int* __restrict__ r3) {
  int ty = threadIdx.x >> 6, lane = threadIdx.x & 63;
  int n = (ty == 0 || ty == 3) ? NE_N : NP_N;
  int nblk = (n + 1023) >> 10;
  int v = (lane < nblk) ? part[ty * 64 + lane] : 0;
  int sc = v;
#pragma unroll
  for (int off = 1; off < 64; off <<= 1) {
    int t = __shfl_up(sc, off, 64);
    if (lane >= off) sc += t;
  }
  if (lane < nblk) part_excl[ty * 64 + lane] = sc - v;
  if (lane == nblk - 1) {
    int* rp = ty == 0 ? r0 : ty == 1 ? r1 : ty == 2 ? r2 : r3;
    rp[n] = sc;  // total
  }
}

// phase C: write exclusive scan to rp + cursor. grid (49, 4)
__global__ __launch_bounds__(256) void scanC_k(
    const int* __restrict__ c0, const int* __restrict__ c1,
    const int* __restrict__ c2, const int* __restrict__ c3,
    int* __restrict__ r0, int* __restrict__ r1, int* __restrict__ r2,
    int* __restrict__ r3, int* __restrict__ u0, int* __restrict__ u1,
    int* __restrict__ u2, int* __restrict__ u3,
    const int* __restrict__ part_excl) {
  int ty = blockIdx.y;
  const int* cnt = ty == 0 ? c0 : ty == 1 ? c1 : ty == 2 ? c2 : c3;
  int* rp = ty == 0 ? r0 : ty == 1 ? r1 : ty == 2 ? r2 : r3;
  int* cur = ty == 0 ? u0 : ty == 1 ? u1 : ty == 2 ? u2 : u3;
  int n = (ty == 0 || ty == 3) ? NE_N : NP_N;
  int nblk = (n + 1023) >> 10;
  if ((int)blockIdx.x >= nblk) return;
  int base = blockIdx.x * 1024 + threadIdx.x * 4;
  int v[4];
#pragma unroll
  for (int j = 0; j < 4; j++) v[j] = (base + j < n) ? cnt[base + j] : 0;
  int s = v[0] + v[1] + v[2] + v[3];
  int lane = threadIdx.x & 63, wid = threadIdx.x >> 6;
  int sc = s;
#pragma unroll
  for (int off = 1; off < 64; off <<= 1) {
    int t = __shfl_up(sc, off, 64);
    if (lane >= off) sc += t;
  }
  __shared__ int ws4[4];
  if (lane == 63) ws4[wid] = sc;
  __syncthreads();
  int wbase = 0;
  for (int w = 0; w < wid; w++) wbase += ws4[w];
  int p = part_excl[ty * 64 + blockIdx.x] + wbase + sc - s;
#pragma unroll
  for (int j = 0; j < 4; j++) {
    if (base + j < n) { rp[base + j] = p; cur[base + j] = p; }
    p += v[j];
  }
}

// fused fill over 4 types (grid.y = type)
__global__ __launch_bounds__(256) void fill4_k(
    const int* __restrict__ s0, const int* __restrict__ s1,
    const int* __restrict__ s2, const int* __restrict__ s3,
    const int* __restrict__ d0, const int* __restrict__ d1,
    const int* __restrict__ d2, const int* __restrict__ d3,
    int* __restrict__ u0, int* __restrict__ u1, int* __restrict__ u2,
    int* __restrict__ u3, int* __restrict__ o0, int* __restrict__ o1,
    int* __restrict__ o2, int* __restrict__ o3) {
  int ty = blockIdx.y;
  const int* src = ty == 0 ? s0 : ty == 1 ? s1 : ty == 2 ? s2 : s3;
  const int* dst = ty == 0 ? d0 : ty == 1 ? d1 : ty == 2 ? d2 : d3;
  int* cur = ty == 0 ? u0 : ty == 1 ? u1 : ty == 2 ? u2 : u3;
  int* out = ty == 0 ? o0 : ty == 1 ? o1 : ty == 2 ? o2 : o3;
  int e = blockIdx.x * 256 + threadIdx.x;
  if (e < E_N) {
    int pos = atomicAdd(&cur[dst[e]], 1);
    out[pos] = src[e];
  }
}

// ---------------------------------------------------------------------------
// MFMA GEMM: hs_bf16 = xb @ W  ([N,128]@[128,128]) + es = hs @ a_s (fp32).
__global__ __launch_bounds__(256) void gemm_mfma(
    const ushort* __restrict__ xb, const ushort* __restrict__ WbT,
    const float* __restrict__ a_s, ushort* __restrict__ hs,
    float* __restrict__ es, int N) {
  const int wave = threadIdx.x >> 6;
  const int lane = threadIdx.x & 63;
  const int m = lane & 15, quad = lane >> 4;
  const int row0 = blockIdx.x * 64 + wave * 16;
  if (row0 >= N) return;
  int rowA = row0 + m;
  if (rowA >= N) rowA = N - 1;  // clamp loads; stores guarded

  f32x4 acc[8];
#pragma unroll
  for (int f = 0; f < 8; f++) acc[f] = (f32x4){0.f, 0.f, 0.f, 0.f};

  const short8* ap = (const short8*)(xb + (size_t)rowA * DIM + quad * 8);
#pragma unroll
  for (int k0 = 0; k0 < 4; k0++) {
    short8 a = ap[k0 * 4];
#pragma unroll
    for (int f = 0; f < 8; f++) {
      short8 b = *(const short8*)(WbT + (size_t)(f * 16 + m) * DIM + k0 * 32 +
                                  quad * 8);
      acc[f] = __builtin_amdgcn_mfma_f32_16x16x32_bf16(a, b, acc[f], 0, 0, 0);
    }
  }

  float asv[8];
#pragma unroll
  for (int f = 0; f < 8; f++) asv[f] = a_s[f * 16 + m];
  float ep[4];
#pragma unroll
  for (int r = 0; r < 4; r++) {
    float p = 0.f;
#pragma unroll
    for (int f = 0; f < 8; f++) p += acc[f][r] * asv[f];
#pragma unroll
    for (int off = 1; off < 16; off <<= 1) p += __shfl_xor(p, off, 16);
    ep[r] = p;
  }
  if (m == 0) {
#pragma unroll
    for (int r = 0; r < 4; r++) {
      int rr = row0 + quad * 4 + r;
      if (rr < N) es[rr] = ep[r];
    }
  }

#pragma unroll
  for (int f = 0; f < 8; f++) {
#pragma unroll
    for (int r = 0; r < 4; r++) {
      int rr = row0 + quad * 4 + r;
      ushort mine = f2bf(acc[f][r]);
      ushort other = (ushort)__shfl_xor((int)mine, 1, 64);
      if (((m & 1) == 0) && rr < N) {
        ushort2 pk; pk.x = mine; pk.y = other;
        *(ushort2*)&hs[(size_t)rr * DIM + f * 16 + m] = pk;
      }
    }
  }
}

// ---------------------------------------------------------------------------
// Fused dual-type gather, 4-edge-parallel. One 64-lane wave per dst node:
// lanes = 4 edge-slots x 16 sublanes; sublane reads ushort8 (16B) of the src
// row, so a full 256B row is one instruction and 4 edges are in flight.
// Also computes ed (x_d . vec) in-wave for both types. Writes row once.
__global__ __launch_bounds__(256) void gat_gather2(
    const int* __restrict__ rpA, const int* __restrict__ srcA,
    const float* __restrict__ esA, const ushort* __restrict__ hsA,
    const int* __restrict__ rpB, const int* __restrict__ srcB,
    const float* __restrict__ esB, const ushort* __restrict__ hsB,
    const ushort* __restrict__ xd, const float* __restrict__ vecA,
    const float* __restrict__ vecB, const float* __restrict__ b0,
    const float* __restrict__ b1, ushort* __restrict__ outb, int Nd) {
  const int lane = threadIdx.x & 63;
  const int slot = lane >> 4, sub = lane & 15;
  const int node = (blockIdx.x * 256 + threadIdx.x) >> 6;
  if (node >= Nd) return;

  // ed for both halves: dot(xd[node], vec{A,B}) — reduce over 16 sublanes
  float edvA = 0.f, edvB = 0.f;
  {
    ushort8 xr = *(const ushort8*)&xd[(size_t)node * DIM + sub * 8];
    float4 va0 = *(const float4*)&vecA[sub * 8];
    float4 va1 = *(const float4*)&vecA[sub * 8 + 4];
    float4 vb0 = *(const float4*)&vecB[sub * 8];
    float4 vb1 = *(const float4*)&vecB[sub * 8 + 4];
    float x0 = bf2f(xr[0]), x1 = bf2f(xr[1]), x2 = bf2f(xr[2]),
          x3 = bf2f(xr[3]), x4 = bf2f(xr[4]), x5 = bf2f(xr[5]),
          x6 = bf2f(xr[6]), x7 = bf2f(xr[7]);
    edvA = x0 * va0.x + x1 * va0.y + x2 * va0.z + x3 * va0.w + x4 * va1.x +
           x5 * va1.y + x6 * va1.z + x7 * va1.w;
    edvB = x0 * vb0.x + x1 * vb0.y + x2 * vb0.z + x3 * vb0.w + x4 * vb1.x +
           x5 * vb1.y + x6 * vb1.z + x7 * vb1.w;
#pragma unroll
    for (int off = 8; off >= 1; off >>= 1) {
      edvA += __shfl_xor(edvA, off, 16);
      edvB += __shfl_xor(edvB, off, 16);
    }
  }

  float acc[8];
#pragma unroll
  for (int j = 0; j < 8; j++) acc[j] = 0.f;

#pragma unroll
  for (int half = 0; half < 2; half++) {
    const int* rp = half ? rpB : rpA;
    const int* ss = half ? srcB : srcA;
    const float* es = half ? esB : esA;
    const ushort* hs = half ? hsB : hsA;
    const float edv = half ? edvB : edvA;
    const int beg = rp[node], end = rp[node + 1];

    float mx = 0.f;
    for (int e = beg + lane; e < end; e += 64)
      mx = fmaxf(mx, fmaxf(es[ss[e]] + edv, 0.f));
#pragma unroll
    for (int off = 32; off > 0; off >>= 1)
      mx = fmaxf(mx, __shfl_xor(mx, off, 64));

    float sm = 0.f;
    for (int e = beg + lane; e < end; e += 64)
      sm += __expf(fmaxf(es[ss[e]] + edv, 0.f) - mx);
#pragma unroll
    for (int off = 32; off > 0; off >>= 1) sm += __shfl_xor(sm, off, 64);
    const float inv = 1.f / fmaxf(sm, 1e-16f);

    // 4 edges in flight (one per slot); 16 sublanes cover the 256B row
    for (int e = beg + slot; e < end; e += 4) {
      int s = ss[e];
      float al = __expf(fmaxf(es[s] + edv, 0.f) - mx) * inv;
      ushort8 h = *(const ushort8*)&hs[(size_t)s * DIM + sub * 8];
#pragma unroll
      for (int j = 0; j < 8; j++) acc[j] += al * bf2f(h[j]);
    }
  }

  // combine the 4 slots' partials
#pragma unroll
  for (int j = 0; j < 8; j++) {
    acc[j] += __shfl_xor(acc[j], 16, 64);
    acc[j] += __shfl_xor(acc[j], 32, 64);
  }

  // lane stores dims d, d+1 where d = sub*8 + slot*2 (coalesced 256B row)
  const int d = sub * 8 + slot * 2;
  float2 bb0 = *(const float2*)&b0[d];
  float2 bb1 = *(const float2*)&b1[d];
  float v0 = acc[slot * 2] + bb0.x + bb1.x;
  float v1 = acc[slot * 2 + 1] + bb0.y + bb1.y;
  ushort2 o; o.x = f2bf(v0); o.y = f2bf(v1);
  *(ushort2*)&outb[(size_t)node * DIM + d] = o;
}

// ---------------------------------------------------------------------------
__global__ __launch_bounds__(256) void colsum_k(
    const ushort* __restrict__ xe, const ushort* __restrict__ xp,
    float* __restrict__ colsum) {
  int tid = blockIdx.x * 256 + threadIdx.x;
  const int stride = 256 * 256;  // multiple of 128 -> fixed column per thread
  float s = 0.f;
  for (int idx = tid; idx < NE_N * DIM; idx += stride) s += bf2f(xe[idx]);
  for (int idx = tid; idx < NP_N * DIM; idx += stride) s += bf2f(xp[idx]);
  __shared__ float ls[256];
  ls[threadIdx.x] = s;
  __syncthreads();
  if (threadIdx.x < 128)
    unsafeAtomicAdd(&colsum[threadIdx.x], ls[threadIdx.x] + ls[threadIdx.x + 128]);
}

// ---------------------------------------------------------------------------
__global__ void final_proj(const float* __restrict__ colsum,
                           const float* __restrict__ lin_W,
                           const float* __restrict__ lin_b,
                           float* __restrict__ out) {
  int j = threadIdx.x;
  if (j >= 2) return;
  float s = 0.f;
#pragma unroll 8
  for (int k = 0; k < DIM; k++) s += colsum[k] * lin_W[k * 2 + j];
  out[j] = s / (float)(NE_N + NP_N) + lin_b[j];
}

// ---------------------------------------------------------------------------
extern "C" void kernel_launch(void* const* d_in, const int* in_sizes, int n_in,
                              void* d_out, int out_size, void* d_ws,
                              size_t ws_size, hipStream_t stream) {
  const float* x_elem  = (const float*)d_in[0];
  const float* x_proc  = (const float*)d_in[1];
  const float* W_src   = (const float*)d_in[2];
  const float* W_dst   = (const float*)d_in[3];
  const float* att_src = (const float*)d_in[4];
  const float* att_dst = (const float*)d_in[5];
  const float* bias    = (const float*)d_in[6];
  const float* lin_W   = (const float*)d_in[7];
  const float* lin_b   = (const float*)d_in[8];
  const int* esrc[4] = {(const int*)d_in[9],  (const int*)d_in[11],
                        (const int*)d_in[13], (const int*)d_in[15]};
  const int* edst[4] = {(const int*)d_in[10], (const int*)d_in[12],
                        (const int*)d_in[14], (const int*)d_in[16]};

  // ---- workspace carve-up (all chunks 16B-aligned) ----
  char* p = (char*)d_ws;
  ushort* xe_bf[2]; ushort* xp_bf[2];
  xe_bf[0] = (ushort*)p; p += (size_t)NE_N * DIM * 2;
  xe_bf[1] = (ushort*)p; p += (size_t)NE_N * DIM * 2;
  xp_bf[0] = (ushort*)p; p += (size_t)NP_N * DIM * 2;
  xp_bf[1] = (ushort*)p; p += (size_t)NP_N * DIM * 2;
  ushort* hsA = (ushort*)p; p += (size_t)NE_N * DIM * 2;  // e-src hs
  ushort* hsB = (ushort*)p; p += (size_t)NP_N * DIM * 2;  // p-src hs
  ushort* WbT = (ushort*)p; p += (size_t)12 * DIM * DIM * 2;
  float* esA = (float*)p; p += NE_N * 4;
  float* esB = (float*)p; p += NE_N * 4;
  float* vec = (float*)p; p += 12 * DIM * 4;
  float* csum = (float*)p; p += DIM * 4;
  int* part = (int*)p; p += 4 * 64 * 4;
  int* part_excl = (int*)p; p += 4 * 64 * 4;
  int* cursor[4];
  for (int t = 0; t < 4; t++) { cursor[t] = (int*)p; p += (NE_N + 4) * 4; }
  int* rp[4]; int* ssrc[4];
  for (int t = 0; t < 4; t++) {
    rp[t] = (int*)p;   p += (NE_N + 4) * 4;
    ssrc[t] = (int*)p; p += (size_t)E_N * 4;
  }

  // ---- setup: conversions, vec, CSR ----
  conv_w_k<<<12, 256, 0, stream>>>(W_src, WbT);
  conv_x_k<<<(NE_N * DIM / 4 + 255) / 256, 256, 0, stream>>>(x_elem, xe_bf[0],
                                                             NE_N * DIM / 4);
  conv_x_k<<<(NP_N * DIM / 4 + 255) / 256, 256, 0, stream>>>(x_proc, xp_bf[0],
                                                             NP_N * DIM / 4);
  precompute_vec_k<<<12, 128, 0, stream>>>(W_dst, att_dst, vec);

  hipMemsetAsync(cursor[0], 0, 4 * (NE_N + 4) * sizeof(int), stream);
  hist4_k<<<dim3((E_N + 255) / 256, 4), 256, 0, stream>>>(
      edst[0], edst[1], edst[2], edst[3], cursor[0], cursor[1], cursor[2],
      cursor[3]);
  scanA_k<<<dim3(49, 4), 256, 0, stream>>>(cursor[0], cursor[1], cursor[2],
                                           cursor[3], part);
  scanB_k<<<1, 256, 0, stream>>>(part, part_excl, rp[0], rp[1], rp[2], rp[3]);
  scanC_k<<<dim3(49, 4), 256, 0, stream>>>(cursor[0], cursor[1], cursor[2],
                                           cursor[3], rp[0], rp[1], rp[2],
                                           rp[3], cursor[0], cursor[1],
                                           cursor[2], cursor[3], part_excl);
  fill4_k<<<dim3((E_N + 255) / 256, 4), 256, 0, stream>>>(
      esrc[0], esrc[1], esrc[2], esrc[3], edst[0], edst[1], edst[2], edst[3],
      cursor[0], cursor[1], cursor[2], cursor[3], ssrc[0], ssrc[1], ssrc[2],
      ssrc[3]);

  // ---- layers ----
  int c = 0;
  for (int l = 0; l < 3; l++) {
    int l0 = l * 4 + 0, l1 = l * 4 + 1, l2 = l * 4 + 2, l3 = l * 4 + 3;
    // e-dst: ee (A, e-src) + pe (B, p-src)
    gemm_mfma<<<(NE_N + 63) / 64, 256, 0, stream>>>(
        xe_bf[c], WbT + (size_t)l0 * DIM * DIM, att_src + l0 * DIM, hsA, esA,
        NE_N);
    gemm_mfma<<<(NP_N + 63) / 64, 256, 0, stream>>>(
        xp_bf[c], WbT + (size_t)l3 * DIM * DIM, att_src + l3 * DIM, hsB, esB,
        NP_N);
    gat_gather2<<<(NE_N * 64 + 255) / 256, 256, 0, stream>>>(
        rp[0], ssrc[0], esA, hsA, rp[3], ssrc[3], esB, hsB, xe_bf[c],
        vec + l0 * DIM, vec + l3 * DIM, bias + l0 * DIM, bias + l3 * DIM,
        xe_bf[1 - c], NE_N);
    // p-dst: ep (A, e-src) + pp (B, p-src)
    gemm_mfma<<<(NE_N + 63) / 64, 256, 0, stream>>>(
        xe_bf[c], WbT + (size_t)l1 * DIM * DIM, att_src + l1 * DIM, hsA, esA,
        NE_N);
    gemm_mfma<<<(NP_N + 63) / 64, 256, 0, stream>>>(
        xp_bf[c], WbT + (size_t)l2 * DIM * DIM, att_src + l2 * DIM, hsB, esB,
        NP_N);
    gat_gather2<<<(NP_N * 64 + 255) / 256, 256, 0, stream>>>(
        rp[1], ssrc[1], esA, hsA, rp[2], ssrc[2], esB, hsB, xp_bf[c],
        vec + l1 * DIM, vec + l2 * DIM, bias + l1 * DIM, bias + l2 * DIM,
        xp_bf[1 - c], NP_N);
    c = 1 - c;
  }

  hipMemsetAsync(csum, 0, DIM * sizeof(float), stream);
  colsum_k<<<256, 256, 0, stream>>>(xe_bf[c], xp_bf[c], csum);
  final_proj<<<1, 64, 0, stream>>>(csum, lin_W, lin_b, (float*)d_out);
}

// Round 5
// 640.466 us; speedup vs baseline: 7.9073x; 1.1520x over previous
//
#include <hip/hip_runtime.h>

#define NE_N 50000
#define NP_N 25000
#define E_N 200000
#define DIM 128

typedef __attribute__((ext_vector_type(8))) short short8;
typedef __attribute__((ext_vector_type(8))) ushort ushort8;
typedef __attribute__((ext_vector_type(4))) float f32x4;

static __device__ __forceinline__ ushort f2bf(float f) {
  unsigned x = __float_as_uint(f);
  return (ushort)((x + 0x7fffu + ((x >> 16) & 1u)) >> 16);  // RNE
}
static __device__ __forceinline__ float bf2f(ushort u) {
  return __uint_as_float(((unsigned)u) << 16);
}

// ---------------------------------------------------------------------------
// W_src [12][128][128] fp32 -> WbT [12][n][k] bf16 (transposed per matrix)
__global__ __launch_bounds__(256) void conv_w_k(const float* __restrict__ W,
                                                ushort* __restrict__ WbT) {
  int lt = blockIdx.x;
  const float* src = W + (size_t)lt * DIM * DIM;
  ushort* dst = WbT + (size_t)lt * DIM * DIM;
  for (int i = threadIdx.x; i < DIM * DIM; i += 256) {
    int k = i >> 7, n = i & 127;
    dst[n * DIM + k] = f2bf(src[i]);
  }
}

// fp32 [n4*4] -> bf16
__global__ __launch_bounds__(256) void conv_x_k(const float* __restrict__ x,
                                                ushort* __restrict__ xb, int n4) {
  int i = blockIdx.x * 256 + threadIdx.x;
  if (i >= n4) return;
  float4 v = *(const float4*)&x[i * 4];
  ushort4 o;
  o.x = f2bf(v.x); o.y = f2bf(v.y); o.z = f2bf(v.z); o.w = f2bf(v.w);
  *(ushort4*)&xb[i * 4] = o;
}

// ---------------------------------------------------------------------------
// vec[lt][i] = sum_j W_dst[lt][i][j] * att_dst[lt][j]  (fp32, full precision)
__global__ __launch_bounds__(128) void precompute_vec_k(
    const float* __restrict__ W_dst, const float* __restrict__ att_dst,
    float* __restrict__ vec) {
  int lt = blockIdx.x;
  int i = threadIdx.x;
  const float* Wd = W_dst + (size_t)lt * DIM * DIM;
  const float* ad = att_dst + lt * DIM;
  float s = 0.f;
#pragma unroll 8
  for (int j = 0; j < DIM; j++) s += Wd[i * DIM + j] * ad[j];
  vec[lt * DIM + i] = s;
}

// ---------------------------------------------------------------------------
// CSR build: fused histogram over 4 edge types (grid.y = type)
__global__ __launch_bounds__(256) void hist4_k(
    const int* __restrict__ d0, const int* __restrict__ d1,
    const int* __restrict__ d2, const int* __restrict__ d3,
    int* __restrict__ c0, int* __restrict__ c1, int* __restrict__ c2,
    int* __restrict__ c3) {
  int ty = blockIdx.y;
  const int* dst = ty == 0 ? d0 : ty == 1 ? d1 : ty == 2 ? d2 : d3;
  int* cnt = ty == 0 ? c0 : ty == 1 ? c1 : ty == 2 ? c2 : c3;
  int e = blockIdx.x * 256 + threadIdx.x;
  if (e < E_N) atomicAdd(&cnt[dst[e]], 1);
}

// phase A: per-1024-block sums. grid (49, 4)
__global__ __launch_bounds__(256) void scanA_k(
    const int* __restrict__ c0, const int* __restrict__ c1,
    const int* __restrict__ c2, const int* __restrict__ c3,
    int* __restrict__ part) {
  int ty = blockIdx.y;
  const int* cnt = ty == 0 ? c0 : ty == 1 ? c1 : ty == 2 ? c2 : c3;
  int n = (ty == 0 || ty == 3) ? NE_N : NP_N;
  int nblk = (n + 1023) >> 10;
  if ((int)blockIdx.x >= nblk) return;
  int base = blockIdx.x * 1024 + threadIdx.x * 4;
  int s = 0;
#pragma unroll
  for (int j = 0; j < 4; j++) s += (base + j < n) ? cnt[base + j] : 0;
  int lane = threadIdx.x & 63, wid = threadIdx.x >> 6;
#pragma unroll
  for (int off = 32; off > 0; off >>= 1) s += __shfl_xor(s, off, 64);
  __shared__ int ws4[4];
  if (lane == 0) ws4[wid] = s;
  __syncthreads();
  if (threadIdx.x == 0)
    part[ty * 64 + blockIdx.x] = ws4[0] + ws4[1] + ws4[2] + ws4[3];
}

// phase B: scan partials (<=49/type), 1 block, wave w = type w
__global__ __launch_bounds__(256) void scanB_k(
    const int* __restrict__ part, int* __restrict__ part_excl,
    int* __restrict__ r0, int* __restrict__ r1, int* __restrict__ r2,
    int* __restrict__ r3) {
  int ty = threadIdx.x >> 6, lane = threadIdx.x & 63;
  int n = (ty == 0 || ty == 3) ? NE_N : NP_N;
  int nblk = (n + 1023) >> 10;
  int v = (lane < nblk) ? part[ty * 64 + lane] : 0;
  int sc = v;
#pragma unroll
  for (int off = 1; off < 64; off <<= 1) {
    int t = __shfl_up(sc, off, 64);
    if (lane >= off) sc += t;
  }
  if (lane < nblk) part_excl[ty * 64 + lane] = sc - v;
  if (lane == nblk - 1) {
    int* rp = ty == 0 ? r0 : ty == 1 ? r1 : ty == 2 ? r2 : r3;
    rp[n] = sc;  // total
  }
}

// phase C: write exclusive scan to rp + cursor. grid (49, 4)
__global__ __launch_bounds__(256) void scanC_k(
    const int* __restrict__ c0, const int* __restrict__ c1,
    const int* __restrict__ c2, const int* __restrict__ c3,
    int* __restrict__ r0, int* __restrict__ r1, int* __restrict__ r2,
    int* __restrict__ r3, int* __restrict__ u0, int* __restrict__ u1,
    int* __restrict__ u2, int* __restrict__ u3,
    const int* __restrict__ part_excl) {
  int ty = blockIdx.y;
  const int* cnt = ty == 0 ? c0 : ty == 1 ? c1 : ty == 2 ? c2 : c3;
  int* rp = ty == 0 ? r0 : ty == 1 ? r1 : ty == 2 ? r2 : r3;
  int* cur = ty == 0 ? u0 : ty == 1 ? u1 : ty == 2 ? u2 : u3;
  int n = (ty == 0 || ty == 3) ? NE_N : NP_N;
  int nblk = (n + 1023) >> 10;
  if ((int)blockIdx.x >= nblk) return;
  int base = blockIdx.x * 1024 + threadIdx.x * 4;
  int v[4];
#pragma unroll
  for (int j = 0; j < 4; j++) v[j] = (base + j < n) ? cnt[base + j] : 0;
  int s = v[0] + v[1] + v[2] + v[3];
  int lane = threadIdx.x & 63, wid = threadIdx.x >> 6;
  int sc = s;
#pragma unroll
  for (int off = 1; off < 64; off <<= 1) {
    int t = __shfl_up(sc, off, 64);
    if (lane >= off) sc += t;
  }
  __shared__ int ws4[4];
  if (lane == 63) ws4[wid] = sc;
  __syncthreads();
  int wbase = 0;
  for (int w = 0; w < wid; w++) wbase += ws4[w];
  int p = part_excl[ty * 64 + blockIdx.x] + wbase + sc - s;
#pragma unroll
  for (int j = 0; j < 4; j++) {
    if (base + j < n) { rp[base + j] = p; cur[base + j] = p; }
    p += v[j];
  }
}

// fused fill over 4 types (grid.y = type)
__global__ __launch_bounds__(256) void fill4_k(
    const int* __restrict__ s0, const int* __restrict__ s1,
    const int* __restrict__ s2, const int* __restrict__ s3,
    const int* __restrict__ d0, const int* __restrict__ d1,
    const int* __restrict__ d2, const int* __restrict__ d3,
    int* __restrict__ u0, int* __restrict__ u1, int* __restrict__ u2,
    int* __restrict__ u3, int* __restrict__ o0, int* __restrict__ o1,
    int* __restrict__ o2, int* __restrict__ o3) {
  int ty = blockIdx.y;
  const int* src = ty == 0 ? s0 : ty == 1 ? s1 : ty == 2 ? s2 : s3;
  const int* dst = ty == 0 ? d0 : ty == 1 ? d1 : ty == 2 ? d2 : d3;
  int* cur = ty == 0 ? u0 : ty == 1 ? u1 : ty == 2 ? u2 : u3;
  int* out = ty == 0 ? o0 : ty == 1 ? o1 : ty == 2 ? o2 : o3;
  int e = blockIdx.x * 256 + threadIdx.x;
  if (e < E_N) {
    int pos = atomicAdd(&cur[dst[e]], 1);
    out[pos] = src[e];
  }
}

// ---------------------------------------------------------------------------
// Dual MFMA GEMM: for one x ([N,128] bf16) and two weights W0,W1 (bf16,
// pre-transposed [n][k]): hs_i = fp8_e4m3(x@W_i), es_i = (x@W_i)@a_i (fp32).
// Block 256 = 4 waves; wave w handles rows [blk*64 + w*16, +16), 128 cols.
__global__ __launch_bounds__(256) void gemm_dual(
    const ushort* __restrict__ xb, const ushort* __restrict__ W0T,
    const ushort* __restrict__ W1T, const float* __restrict__ a0,
    const float* __restrict__ a1, unsigned char* __restrict__ hs0,
    unsigned char* __restrict__ hs1, float* __restrict__ es0,
    float* __restrict__ es1, int N) {
  const int wave = threadIdx.x >> 6;
  const int lane = threadIdx.x & 63;
  const int m = lane & 15, quad = lane >> 4;
  const int row0 = blockIdx.x * 64 + wave * 16;
  if (row0 >= N) return;
  int rowA = row0 + m;
  if (rowA >= N) rowA = N - 1;  // clamp loads; stores guarded

  f32x4 acc0[8], acc1[8];
#pragma unroll
  for (int f = 0; f < 8; f++) {
    acc0[f] = (f32x4){0.f, 0.f, 0.f, 0.f};
    acc1[f] = (f32x4){0.f, 0.f, 0.f, 0.f};
  }

  const short8* ap = (const short8*)(xb + (size_t)rowA * DIM + quad * 8);
#pragma unroll
  for (int k0 = 0; k0 < 4; k0++) {
    short8 a = ap[k0 * 4];
#pragma unroll
    for (int f = 0; f < 8; f++) {
      size_t boff = (size_t)(f * 16 + m) * DIM + k0 * 32 + quad * 8;
      short8 b0 = *(const short8*)(W0T + boff);
      acc0[f] = __builtin_amdgcn_mfma_f32_16x16x32_bf16(a, b0, acc0[f], 0, 0, 0);
      short8 b1 = *(const short8*)(W1T + boff);
      acc1[f] = __builtin_amdgcn_mfma_f32_16x16x32_bf16(a, b1, acc1[f], 0, 0, 0);
    }
  }

#pragma unroll
  for (int set = 0; set < 2; set++) {
    f32x4* acc = set ? acc1 : acc0;
    const float* as = set ? a1 : a0;
    float* es = set ? es1 : es0;
    unsigned char* hs = set ? hs1 : hs0;

    // es: lane holds C[row=quad*4+r][col=f*16+m]
    float asv[8];
#pragma unroll
    for (int f = 0; f < 8; f++) asv[f] = as[f * 16 + m];
#pragma unroll
    for (int r = 0; r < 4; r++) {
      float p = 0.f;
#pragma unroll
      for (int f = 0; f < 8; f++) p += acc[f][r] * asv[f];
#pragma unroll
      for (int off = 1; off < 16; off <<= 1) p += __shfl_xor(p, off, 16);
      if (m == 0) {
        int rr = row0 + quad * 4 + r;
        if (rr < N) es[rr] = p;
      }
    }

    // hs fp8 store: pack 4 cols into a dword, lanes with m%4==0 store
#pragma unroll
    for (int f = 0; f < 8; f++) {
#pragma unroll
      for (int r = 0; r < 4; r++) {
        float v = acc[f][r];
        float v1 = __shfl_xor(v, 1, 64);  // col m^1
        int pk2 = __builtin_amdgcn_cvt_pk_fp8_f32(v, v1, 0, false);
        int pk2b = __shfl_xor(pk2, 2, 64);  // cols m+2,m+3 (on m%4==0)
        int rr = row0 + quad * 4 + r;
        if (((m & 3) == 0) && rr < N) {
          unsigned word = ((unsigned)pk2 & 0xffffu) | ((unsigned)pk2b << 16);
          *(unsigned*)&hs[(size_t)rr * DIM + f * 16 + m] = word;
        }
      }
    }
  }
}

// ---------------------------------------------------------------------------
// Fused dual-type gather, single-pass softmax (logits >= 0 and O(10): exp
// cannot overflow fp32, so no max-subtraction needed; alpha = w/SUMw applied
// after the accumulate). hs is fp8 e4m3. One 64-lane wave per dst node:
// 4 edge-slots x 16 sublanes; sublane reads 8B (8 fp8) of the 128B row.
__global__ __launch_bounds__(256) void gat_gather2(
    const int* __restrict__ rpA, const int* __restrict__ srcA,
    const float* __restrict__ esA, const unsigned char* __restrict__ hsA,
    const int* __restrict__ rpB, const int* __restrict__ srcB,
    const float* __restrict__ esB, const unsigned char* __restrict__ hsB,
    const ushort* __restrict__ xd, const float* __restrict__ vecA,
    const float* __restrict__ vecB, const float* __restrict__ b0,
    const float* __restrict__ b1, ushort* __restrict__ outb, int Nd) {
  const int lane = threadIdx.x & 63;
  const int slot = lane >> 4, sub = lane & 15;
  const int node = (blockIdx.x * 256 + threadIdx.x) >> 6;
  if (node >= Nd) return;

  // ed for both halves: dot(xd[node], vec{A,B}) — reduce over 16 sublanes
  float edvA = 0.f, edvB = 0.f;
  {
    ushort8 xr = *(const ushort8*)&xd[(size_t)node * DIM + sub * 8];
    float4 va0 = *(const float4*)&vecA[sub * 8];
    float4 va1 = *(const float4*)&vecA[sub * 8 + 4];
    float4 vb0 = *(const float4*)&vecB[sub * 8];
    float4 vb1 = *(const float4*)&vecB[sub * 8 + 4];
    float x0 = bf2f(xr[0]), x1 = bf2f(xr[1]), x2 = bf2f(xr[2]),
          x3 = bf2f(xr[3]), x4 = bf2f(xr[4]), x5 = bf2f(xr[5]),
          x6 = bf2f(xr[6]), x7 = bf2f(xr[7]);
    edvA = x0 * va0.x + x1 * va0.y + x2 * va0.z + x3 * va0.w + x4 * va1.x +
           x5 * va1.y + x6 * va1.z + x7 * va1.w;
    edvB = x0 * vb0.x + x1 * vb0.y + x2 * vb0.z + x3 * vb0.w + x4 * vb1.x +
           x5 * vb1.y + x6 * vb1.z + x7 * vb1.w;
#pragma unroll
    for (int off = 8; off >= 1; off >>= 1) {
      edvA += __shfl_xor(edvA, off, 16);
      edvB += __shfl_xor(edvB, off, 16);
    }
  }

  float res[8];
#pragma unroll
  for (int j = 0; j < 8; j++) res[j] = 0.f;

#pragma unroll
  for (int half = 0; half < 2; half++) {
    const int* rp = half ? rpB : rpA;
    const int* ss = half ? srcB : srcA;
    const float* es = half ? esB : esA;
    const unsigned char* hs = half ? hsB : hsA;
    const float edv = half ? edvB : edvA;
    const int beg = rp[node], end = rp[node + 1];

    float acc[8];
#pragma unroll
    for (int j = 0; j < 8; j++) acc[j] = 0.f;
    float sw = 0.f;

    // single pass: w = exp(relu(es+ed)); acc += w*h; sw += w
    for (int e = beg + slot; e < end; e += 4) {
      int s = ss[e];
      float w = __expf(fmaxf(es[s] + edv, 0.f));
      sw += w;
      uint2 h = *(const uint2*)&hs[(size_t)s * DIM + sub * 8];
      auto p01 = __builtin_amdgcn_cvt_pk_f32_fp8((int)h.x, false);
      auto p23 = __builtin_amdgcn_cvt_pk_f32_fp8((int)h.x, true);
      auto p45 = __builtin_amdgcn_cvt_pk_f32_fp8((int)h.y, false);
      auto p67 = __builtin_amdgcn_cvt_pk_f32_fp8((int)h.y, true);
      acc[0] += w * p01[0]; acc[1] += w * p01[1];
      acc[2] += w * p23[0]; acc[3] += w * p23[1];
      acc[4] += w * p45[0]; acc[5] += w * p45[1];
      acc[6] += w * p67[0]; acc[7] += w * p67[1];
    }

    // combine the 4 slots (lane bits 4,5), then normalize
#pragma unroll
    for (int j = 0; j < 8; j++) {
      acc[j] += __shfl_xor(acc[j], 16, 64);
      acc[j] += __shfl_xor(acc[j], 32, 64);
    }
    sw += __shfl_xor(sw, 16, 64);
    sw += __shfl_xor(sw, 32, 64);
    const float inv = 1.f / fmaxf(sw, 1e-16f);
#pragma unroll
    for (int j = 0; j < 8; j++) res[j] += acc[j] * inv;
  }

  // lane stores dims d, d+1 where d = sub*8 + slot*2 (coalesced 256B row)
  const int d = sub * 8 + slot * 2;
  float2 bb0 = *(const float2*)&b0[d];
  float2 bb1 = *(const float2*)&b1[d];
  float v0 = res[slot * 2] + bb0.x + bb1.x;
  float v1 = res[slot * 2 + 1] + bb0.y + bb1.y;
  ushort2 o; o.x = f2bf(v0); o.y = f2bf(v1);
  *(ushort2*)&outb[(size_t)node * DIM + d] = o;
}

// ---------------------------------------------------------------------------
__global__ __launch_bounds__(256) void colsum_k(
    const ushort* __restrict__ xe, const ushort* __restrict__ xp,
    float* __restrict__ colsum) {
  int tid = blockIdx.x * 256 + threadIdx.x;
  const int stride = 256 * 256;  // multiple of 128 -> fixed column per thread
  float s = 0.f;
  for (int idx = tid; idx < NE_N * DIM; idx += stride) s += bf2f(xe[idx]);
  for (int idx = tid; idx < NP_N * DIM; idx += stride) s += bf2f(xp[idx]);
  __shared__ float ls[256];
  ls[threadIdx.x] = s;
  __syncthreads();
  if (threadIdx.x < 128)
    unsafeAtomicAdd(&colsum[threadIdx.x], ls[threadIdx.x] + ls[threadIdx.x + 128]);
}

// ---------------------------------------------------------------------------
__global__ void final_proj(const float* __restrict__ colsum,
                           const float* __restrict__ lin_W,
                           const float* __restrict__ lin_b,
                           float* __restrict__ out) {
  int j = threadIdx.x;
  if (j >= 2) return;
  float s = 0.f;
#pragma unroll 8
  for (int k = 0; k < DIM; k++) s += colsum[k] * lin_W[k * 2 + j];
  out[j] = s / (float)(NE_N + NP_N) + lin_b[j];
}

// ---------------------------------------------------------------------------
extern "C" void kernel_launch(void* const* d_in, const int* in_sizes, int n_in,
                              void* d_out, int out_size, void* d_ws,
                              size_t ws_size, hipStream_t stream) {
  const float* x_elem  = (const float*)d_in[0];
  const float* x_proc  = (const float*)d_in[1];
  const float* W_src   = (const float*)d_in[2];
  const float* W_dst   = (const float*)d_in[3];
  const float* att_src = (const float*)d_in[4];
  const float* att_dst = (const float*)d_in[5];
  const float* bias    = (const float*)d_in[6];
  const float* lin_W   = (const float*)d_in[7];
  const float* lin_b   = (const float*)d_in[8];
  const int* esrc[4] = {(const int*)d_in[9],  (const int*)d_in[11],
                        (const int*)d_in[13], (const int*)d_in[15]};
  const int* edst[4] = {(const int*)d_in[10], (const int*)d_in[12],
                        (const int*)d_in[14], (const int*)d_in[16]};

  // ---- workspace carve-up (16B-aligned chunks) ----
  char* p = (char*)d_ws;
  ushort* xe_bf[2]; ushort* xp_bf[2];
  xe_bf[0] = (ushort*)p; p += (size_t)NE_N * DIM * 2;
  xe_bf[1] = (ushort*)p; p += (size_t)NE_N * DIM * 2;
  xp_bf[0] = (ushort*)p; p += (size_t)NP_N * DIM * 2;
  xp_bf[1] = (ushort*)p; p += (size_t)NP_N * DIM * 2;
  unsigned char* hsE0 = (unsigned char*)p; p += (size_t)NE_N * DIM;  // W[l,0]
  unsigned char* hsE1 = (unsigned char*)p; p += (size_t)NE_N * DIM;  // W[l,1]
  unsigned char* hsP3 = (unsigned char*)p; p += (size_t)NP_N * DIM;  // W[l,3]
  unsigned char* hsP2 = (unsigned char*)p; p += (size_t)NP_N * DIM;  // W[l,2]
  ushort* WbT = (ushort*)p; p += (size_t)12 * DIM * DIM * 2;
  float* esE0 = (float*)p; p += (size_t)NE_N * 4;
  float* esE1 = (float*)p; p += (size_t)NE_N * 4;
  float* esP3 = (float*)p; p += (size_t)NP_N * 4;
  float* esP2 = (float*)p; p += (size_t)NP_N * 4;
  float* vec = (float*)p; p += 12 * DIM * 4;
  float* csum = (float*)p; p += DIM * 4;
  int* part = (int*)p; p += 4 * 64 * 4;
  int* part_excl = (int*)p; p += 4 * 64 * 4;
  int* cursor[4];
  for (int t = 0; t < 4; t++) { cursor[t] = (int*)p; p += (NE_N + 4) * 4; }
  int* rp[4]; int* ssrc[4];
  for (int t = 0; t < 4; t++) {
    rp[t] = (int*)p;   p += (NE_N + 4) * 4;
    ssrc[t] = (int*)p; p += (size_t)E_N * 4;
  }

  // ---- setup: conversions, vec, CSR ----
  conv_w_k<<<12, 256, 0, stream>>>(W_src, WbT);
  conv_x_k<<<(NE_N * DIM / 4 + 255) / 256, 256, 0, stream>>>(x_elem, xe_bf[0],
                                                             NE_N * DIM / 4);
  conv_x_k<<<(NP_N * DIM / 4 + 255) / 256, 256, 0, stream>>>(x_proc, xp_bf[0],
                                                             NP_N * DIM / 4);
  precompute_vec_k<<<12, 128, 0, stream>>>(W_dst, att_dst, vec);

  hipMemsetAsync(cursor[0], 0, 4 * (NE_N + 4) * sizeof(int), stream);
  hist4_k<<<dim3((E_N + 255) / 256, 4), 256, 0, stream>>>(
      edst[0], edst[1], edst[2], edst[3], cursor[0], cursor[1], cursor[2],
      cursor[3]);
  scanA_k<<<dim3(49, 4), 256, 0, stream>>>(cursor[0], cursor[1], cursor[2],
                                           cursor[3], part);
  scanB_k<<<1, 256, 0, stream>>>(part, part_excl, rp[0], rp[1], rp[2], rp[3]);
  scanC_k<<<dim3(49, 4), 256, 0, stream>>>(cursor[0], cursor[1], cursor[2],
                                           cursor[3], rp[0], rp[1], rp[2],
                                           rp[3], cursor[0], cursor[1],
                                           cursor[2], cursor[3], part_excl);
  fill4_k<<<dim3((E_N + 255) / 256, 4), 256, 0, stream>>>(
      esrc[0], esrc[1], esrc[2], esrc[3], edst[0], edst[1], edst[2], edst[3],
      cursor[0], cursor[1], cursor[2], cursor[3], ssrc[0], ssrc[1], ssrc[2],
      ssrc[3]);

  // ---- layers ----
  int c = 0;
  for (int l = 0; l < 3; l++) {
    int l0 = l * 4 + 0, l1 = l * 4 + 1, l2 = l * 4 + 2, l3 = l * 4 + 3;
    // e-src dual gemm: W[l,0] (for ee) + W[l,1] (for ep)
    gemm_dual<<<(NE_N + 63) / 64, 256, 0, stream>>>(
        xe_bf[c], WbT + (size_t)l0 * DIM * DIM, WbT + (size_t)l1 * DIM * DIM,
        att_src + l0 * DIM, att_src + l1 * DIM, hsE0, hsE1, esE0, esE1, NE_N);
    // p-src dual gemm: W[l,3] (for pe) + W[l,2] (for pp)
    gemm_dual<<<(NP_N + 63) / 64, 256, 0, stream>>>(
        xp_bf[c], WbT + (size_t)l3 * DIM * DIM, WbT + (size_t)l2 * DIM * DIM,
        att_src + l3 * DIM, att_src + l2 * DIM, hsP3, hsP2, esP3, esP2, NP_N);
    // e-dst gather: ee (A) + pe (B)
    gat_gather2<<<(NE_N * 64 + 255) / 256, 256, 0, stream>>>(
        rp[0], ssrc[0], esE0, hsE0, rp[3], ssrc[3], esP3, hsP3, xe_bf[c],
        vec + l0 * DIM, vec + l3 * DIM, bias + l0 * DIM, bias + l3 * DIM,
        xe_bf[1 - c], NE_N);
    // p-dst gather: ep (A) + pp (B)
    gat_gather2<<<(NP_N * 64 + 255) / 256, 256, 0, stream>>>(
        rp[1], ssrc[1], esE1, hsE1, rp[2], ssrc[2], esP2, hsP2, xp_bf[c],
        vec + l1 * DIM, vec + l2 * DIM, bias + l1 * DIM, bias + l2 * DIM,
        xp_bf[1 - c], NP_N);
    c = 1 - c;
  }

  hipMemsetAsync(csum, 0, DIM * sizeof(float), stream);
  colsum_k<<<256, 256, 0, stream>>>(xe_bf[c], xp_bf[c], csum);
  final_proj<<<1, 64, 0, stream>>>(csum, lin_W, lin_b, (float*)d_out);
}

// Round 6
// 608.780 us; speedup vs baseline: 8.3189x; 1.0520x over previous
//
#include <hip/hip_runtime.h>

#define NE_N 50000
#define NP_N 25000
#define E_N 200000
#define DIM 128

typedef __attribute__((ext_vector_type(8))) short short8;
typedef __attribute__((ext_vector_type(8))) ushort ushort8;
typedef __attribute__((ext_vector_type(4))) float f32x4;

static __device__ __forceinline__ ushort f2bf(float f) {
  unsigned x = __float_as_uint(f);
  return (ushort)((x + 0x7fffu + ((x >> 16) & 1u)) >> 16);  // RNE
}
static __device__ __forceinline__ float bf2f(ushort u) {
  return __uint_as_float(((unsigned)u) << 16);
}

// ---------------------------------------------------------------------------
// W_src [12][128][128] fp32 -> WbT [12][n][k] bf16 (transposed per matrix)
__global__ __launch_bounds__(256) void conv_w_k(const float* __restrict__ W,
                                                ushort* __restrict__ WbT) {
  int lt = blockIdx.x;
  const float* src = W + (size_t)lt * DIM * DIM;
  ushort* dst = WbT + (size_t)lt * DIM * DIM;
  for (int i = threadIdx.x; i < DIM * DIM; i += 256) {
    int k = i >> 7, n = i & 127;
    dst[n * DIM + k] = f2bf(src[i]);
  }
}

// fp32 -> bf16 for both feature matrices in one dispatch
__global__ __launch_bounds__(256) void conv_x2_k(const float* __restrict__ xe,
                                                 const float* __restrict__ xp,
                                                 ushort* __restrict__ xeb,
                                                 ushort* __restrict__ xpb) {
  const int n4e = NE_N * DIM / 4;
  const int n4p = NP_N * DIM / 4;
  int i = blockIdx.x * 256 + threadIdx.x;
  const float* x;
  ushort* xb;
  if (i < n4e) {
    x = xe; xb = xeb;
  } else {
    i -= n4e;
    if (i >= n4p) return;
    x = xp; xb = xpb;
  }
  float4 v = *(const float4*)&x[(size_t)i * 4];
  ushort4 o;
  o.x = f2bf(v.x); o.y = f2bf(v.y); o.z = f2bf(v.z); o.w = f2bf(v.w);
  *(ushort4*)&xb[(size_t)i * 4] = o;
}

// ---------------------------------------------------------------------------
// vec[lt][i] = sum_j W_dst[lt][i][j] * att_dst[lt][j]  (fp32, full precision)
__global__ __launch_bounds__(128) void precompute_vec_k(
    const float* __restrict__ W_dst, const float* __restrict__ att_dst,
    float* __restrict__ vec) {
  int lt = blockIdx.x;
  int i = threadIdx.x;
  const float* Wd = W_dst + (size_t)lt * DIM * DIM;
  const float* ad = att_dst + lt * DIM;
  float s = 0.f;
#pragma unroll 8
  for (int j = 0; j < DIM; j++) s += Wd[i * DIM + j] * ad[j];
  vec[lt * DIM + i] = s;
}

// ---------------------------------------------------------------------------
// CSR build: fused histogram over 4 edge types (grid.y = type)
__global__ __launch_bounds__(256) void hist4_k(
    const int* __restrict__ d0, const int* __restrict__ d1,
    const int* __restrict__ d2, const int* __restrict__ d3,
    int* __restrict__ c0, int* __restrict__ c1, int* __restrict__ c2,
    int* __restrict__ c3) {
  int ty = blockIdx.y;
  const int* dst = ty == 0 ? d0 : ty == 1 ? d1 : ty == 2 ? d2 : d3;
  int* cnt = ty == 0 ? c0 : ty == 1 ? c1 : ty == 2 ? c2 : c3;
  int e = blockIdx.x * 256 + threadIdx.x;
  if (e < E_N) atomicAdd(&cnt[dst[e]], 1);
}

// phase A: per-1024-block sums. grid (49, 4)
__global__ __launch_bounds__(256) void scanA_k(
    const int* __restrict__ c0, const int* __restrict__ c1,
    const int* __restrict__ c2, const int* __restrict__ c3,
    int* __restrict__ part) {
  int ty = blockIdx.y;
  const int* cnt = ty == 0 ? c0 : ty == 1 ? c1 : ty == 2 ? c2 : c3;
  int n = (ty == 0 || ty == 3) ? NE_N : NP_N;
  int nblk = (n + 1023) >> 10;
  if ((int)blockIdx.x >= nblk) return;
  int base = blockIdx.x * 1024 + threadIdx.x * 4;
  int s = 0;
#pragma unroll
  for (int j = 0; j < 4; j++) s += (base + j < n) ? cnt[base + j] : 0;
  int lane = threadIdx.x & 63, wid = threadIdx.x >> 6;
#pragma unroll
  for (int off = 32; off > 0; off >>= 1) s += __shfl_xor(s, off, 64);
  __shared__ int ws4[4];
  if (lane == 0) ws4[wid] = s;
  __syncthreads();
  if (threadIdx.x == 0)
    part[ty * 64 + blockIdx.x] = ws4[0] + ws4[1] + ws4[2] + ws4[3];
}

// phase B: scan partials (<=49/type), 1 block, wave w = type w
__global__ __launch_bounds__(256) void scanB_k(
    const int* __restrict__ part, int* __restrict__ part_excl,
    int* __restrict__ r0, int* __restrict__ r1, int* __restrict__ r2,
    int* __restrict__ r3) {
  int ty = threadIdx.x >> 6, lane = threadIdx.x & 63;
  int n = (ty == 0 || ty == 3) ? NE_N : NP_N;
  int nblk = (n + 1023) >> 10;
  int v = (lane < nblk) ? part[ty * 64 + lane] : 0;
  int sc = v;
#pragma unroll
  for (int off = 1; off < 64; off <<= 1) {
    int t = __shfl_up(sc, off, 64);
    if (lane >= off) sc += t;
  }
  if (lane < nblk) part_excl[ty * 64 + lane] = sc - v;
  if (lane == nblk - 1) {
    int* rp = ty == 0 ? r0 : ty == 1 ? r1 : ty == 2 ? r2 : r3;
    rp[n] = sc;  // total
  }
}

// phase C: write exclusive scan to rp + cursor. grid (49, 4)
__global__ __launch_bounds__(256) void scanC_k(
    const int* __restrict__ c0, const int* __restrict__ c1,
    const int* __restrict__ c2, const int* __restrict__ c3,
    int* __restrict__ r0, int* __restrict__ r1, int* __restrict__ r2,
    int* __restrict__ r3, int* __restrict__ u0, int* __restrict__ u1,
    int* __restrict__ u2, int* __restrict__ u3,
    const int* __restrict__ part_excl) {
  int ty = blockIdx.y;
  const int* cnt = ty == 0 ? c0 : ty == 1 ? c1 : ty == 2 ? c2 : c3;
  int* rp = ty == 0 ? r0 : ty == 1 ? r1 : ty == 2 ? r2 : r3;
  int* cur = ty == 0 ? u0 : ty == 1 ? u1 : ty == 2 ? u2 : u3;
  int n = (ty == 0 || ty == 3) ? NE_N : NP_N;
  int nblk = (n + 1023) >> 10;
  if ((int)blockIdx.x >= nblk) return;
  int base = blockIdx.x * 1024 + threadIdx.x * 4;
  int v[4];
#pragma unroll
  for (int j = 0; j < 4; j++) v[j] = (base + j < n) ? cnt[base + j] : 0;
  int s = v[0] + v[1] + v[2] + v[3];
  int lane = threadIdx.x & 63, wid = threadIdx.x >> 6;
  int sc = s;
#pragma unroll
  for (int off = 1; off < 64; off <<= 1) {
    int t = __shfl_up(sc, off, 64);
    if (lane >= off) sc += t;
  }
  __shared__ int ws4[4];
  if (lane == 63) ws4[wid] = sc;
  __syncthreads();
  int wbase = 0;
  for (int w = 0; w < wid; w++) wbase += ws4[w];
  int p = part_excl[ty * 64 + blockIdx.x] + wbase + sc - s;
#pragma unroll
  for (int j = 0; j < 4; j++) {
    if (base + j < n) { rp[base + j] = p; cur[base + j] = p; }
    p += v[j];
  }
}

// fused fill over 4 types (grid.y = type); ssrc stored as ushort (ids < 64K)
__global__ __launch_bounds__(256) void fill4_k(
    const int* __restrict__ s0, const int* __restrict__ s1,
    const int* __restrict__ s2, const int* __restrict__ s3,
    const int* __restrict__ d0, const int* __restrict__ d1,
    const int* __restrict__ d2, const int* __restrict__ d3,
    int* __restrict__ u0, int* __restrict__ u1, int* __restrict__ u2,
    int* __restrict__ u3, ushort* __restrict__ o0, ushort* __restrict__ o1,
    ushort* __restrict__ o2, ushort* __restrict__ o3) {
  int ty = blockIdx.y;
  const int* src = ty == 0 ? s0 : ty == 1 ? s1 : ty == 2 ? s2 : s3;
  const int* dst = ty == 0 ? d0 : ty == 1 ? d1 : ty == 2 ? d2 : d3;
  int* cur = ty == 0 ? u0 : ty == 1 ? u1 : ty == 2 ? u2 : u3;
  ushort* out = ty == 0 ? o0 : ty == 1 ? o1 : ty == 2 ? o2 : o3;
  int e = blockIdx.x * 256 + threadIdx.x;
  if (e < E_N) {
    int pos = atomicAdd(&cur[dst[e]], 1);
    out[pos] = (ushort)src[e];
  }
}

// ---------------------------------------------------------------------------
// Combined dual MFMA GEMM for both source types in one dispatch.
// Per source x ([N,128] bf16) and two weights (bf16, pre-transposed [n][k]):
// hs_i = fp8_e4m3(x@W_i), es_i = (x@W_i)@a_i (fp32).
#define EBLK ((NE_N + 63) / 64)
#define PBLK ((NP_N + 63) / 64)
__global__ __launch_bounds__(256) void gemm_dual2(
    const ushort* __restrict__ xe, const ushort* __restrict__ xp,
    const ushort* __restrict__ WbT, const float* __restrict__ att, int l,
    unsigned char* __restrict__ hsE0, unsigned char* __restrict__ hsE1,
    unsigned char* __restrict__ hsP3, unsigned char* __restrict__ hsP2,
    float* __restrict__ esE0, float* __restrict__ esE1,
    float* __restrict__ esP3, float* __restrict__ esP2) {
  int blk = blockIdx.x;
  const ushort* xb;
  const ushort *W0T, *W1T;
  const float *a0, *a1;
  unsigned char *hs0, *hs1;
  float *es0, *es1;
  int N;
  if (blk < EBLK) {
    xb = xe; N = NE_N;
    W0T = WbT + (size_t)(l * 4 + 0) * DIM * DIM;
    W1T = WbT + (size_t)(l * 4 + 1) * DIM * DIM;
    a0 = att + (l * 4 + 0) * DIM; a1 = att + (l * 4 + 1) * DIM;
    hs0 = hsE0; hs1 = hsE1; es0 = esE0; es1 = esE1;
  } else {
    blk -= EBLK; xb = xp; N = NP_N;
    W0T = WbT + (size_t)(l * 4 + 3) * DIM * DIM;
    W1T = WbT + (size_t)(l * 4 + 2) * DIM * DIM;
    a0 = att + (l * 4 + 3) * DIM; a1 = att + (l * 4 + 2) * DIM;
    hs0 = hsP3; hs1 = hsP2; es0 = esP3; es1 = esP2;
  }

  const int wave = threadIdx.x >> 6;
  const int lane = threadIdx.x & 63;
  const int m = lane & 15, quad = lane >> 4;
  const int row0 = blk * 64 + wave * 16;
  if (row0 >= N) return;
  int rowA = row0 + m;
  if (rowA >= N) rowA = N - 1;  // clamp loads; stores guarded

  f32x4 acc0[8], acc1[8];
#pragma unroll
  for (int f = 0; f < 8; f++) {
    acc0[f] = (f32x4){0.f, 0.f, 0.f, 0.f};
    acc1[f] = (f32x4){0.f, 0.f, 0.f, 0.f};
  }

  const short8* ap = (const short8*)(xb + (size_t)rowA * DIM + quad * 8);
#pragma unroll
  for (int k0 = 0; k0 < 4; k0++) {
    short8 a = ap[k0 * 4];
#pragma unroll
    for (int f = 0; f < 8; f++) {
      size_t boff = (size_t)(f * 16 + m) * DIM + k0 * 32 + quad * 8;
      short8 b0 = *(const short8*)(W0T + boff);
      acc0[f] = __builtin_amdgcn_mfma_f32_16x16x32_bf16(a, b0, acc0[f], 0, 0, 0);
      short8 b1 = *(const short8*)(W1T + boff);
      acc1[f] = __builtin_amdgcn_mfma_f32_16x16x32_bf16(a, b1, acc1[f], 0, 0, 0);
    }
  }

#pragma unroll
  for (int set = 0; set < 2; set++) {
    f32x4* acc = set ? acc1 : acc0;
    const float* as = set ? a1 : a0;
    float* es = set ? es1 : es0;
    unsigned char* hs = set ? hs1 : hs0;

    float asv[8];
#pragma unroll
    for (int f = 0; f < 8; f++) asv[f] = as[f * 16 + m];
#pragma unroll
    for (int r = 0; r < 4; r++) {
      float p = 0.f;
#pragma unroll
      for (int f = 0; f < 8; f++) p += acc[f][r] * asv[f];
#pragma unroll
      for (int off = 1; off < 16; off <<= 1) p += __shfl_xor(p, off, 16);
      if (m == 0) {
        int rr = row0 + quad * 4 + r;
        if (rr < N) es[rr] = p;
      }
    }

#pragma unroll
    for (int f = 0; f < 8; f++) {
#pragma unroll
      for (int r = 0; r < 4; r++) {
        float v = acc[f][r];
        float v1 = __shfl_xor(v, 1, 64);  // col m^1
        int pk2 = __builtin_amdgcn_cvt_pk_fp8_f32(v, v1, 0, false);
        int pk2b = __shfl_xor(pk2, 2, 64);  // cols m+2,m+3 (on m%4==0)
        int rr = row0 + quad * 4 + r;
        if (((m & 3) == 0) && rr < N) {
          unsigned word = ((unsigned)pk2 & 0xffffu) | ((unsigned)pk2b << 16);
          *(unsigned*)&hs[(size_t)rr * DIM + f * 16 + m] = word;
        }
      }
    }
  }
}

// ---------------------------------------------------------------------------
// Combined dual-type gather for both dst types in one dispatch.
// Single-pass softmax (logits >= 0, O(10): exp can't overflow fp32).
// hs is fp8 e4m3; ssrc is ushort. One 64-lane wave per dst node:
// 4 edge-slots x 16 sublanes; sublane reads 8B (8 fp8) of the 128B row.
__global__ __launch_bounds__(256) void gat_gather_all(
    const int* __restrict__ rp0, const ushort* __restrict__ ss0,
    const int* __restrict__ rp1, const ushort* __restrict__ ss1,
    const int* __restrict__ rp2, const ushort* __restrict__ ss2,
    const int* __restrict__ rp3, const ushort* __restrict__ ss3,
    const float* __restrict__ esE0, const unsigned char* __restrict__ hsE0,
    const float* __restrict__ esE1, const unsigned char* __restrict__ hsE1,
    const float* __restrict__ esP3, const unsigned char* __restrict__ hsP3,
    const float* __restrict__ esP2, const unsigned char* __restrict__ hsP2,
    const ushort* __restrict__ xe, const ushort* __restrict__ xp,
    const float* __restrict__ vec, const float* __restrict__ bias, int l,
    ushort* __restrict__ outxe, ushort* __restrict__ outxp) {
  const int wid = (blockIdx.x * 256 + threadIdx.x) >> 6;
  const int lane = threadIdx.x & 63;
  const int slot = lane >> 4, sub = lane & 15;

  int node;
  const int *rpA, *rpB;
  const ushort *ssA, *ssB;
  const float *esA, *esB;
  const unsigned char *hsA, *hsB;
  const ushort* xd;
  const float *vecA, *vecB, *b0, *b1;
  ushort* outb;
  if (wid < NE_N) {  // e-dst: ee (A) + pe (B)
    node = wid;
    rpA = rp0; ssA = ss0; esA = esE0; hsA = hsE0;
    rpB = rp3; ssB = ss3; esB = esP3; hsB = hsP3;
    xd = xe;
    vecA = vec + (l * 4 + 0) * DIM; vecB = vec + (l * 4 + 3) * DIM;
    b0 = bias + (l * 4 + 0) * DIM; b1 = bias + (l * 4 + 3) * DIM;
    outb = outxe;
  } else if (wid < NE_N + NP_N) {  // p-dst: ep (A) + pp (B)
    node = wid - NE_N;
    rpA = rp1; ssA = ss1; esA = esE1; hsA = hsE1;
    rpB = rp2; ssB = ss2; esB = esP2; hsB = hsP2;
    xd = xp;
    vecA = vec + (l * 4 + 1) * DIM; vecB = vec + (l * 4 + 2) * DIM;
    b0 = bias + (l * 4 + 1) * DIM; b1 = bias + (l * 4 + 2) * DIM;
    outb = outxp;
  } else {
    return;
  }

  // ed for both halves: dot(xd[node], vec{A,B}) — reduce over 16 sublanes
  float edvA = 0.f, edvB = 0.f;
  {
    ushort8 xr = *(const ushort8*)&xd[(size_t)node * DIM + sub * 8];
    float4 va0 = *(const float4*)&vecA[sub * 8];
    float4 va1 = *(const float4*)&vecA[sub * 8 + 4];
    float4 vb0 = *(const float4*)&vecB[sub * 8];
    float4 vb1 = *(const float4*)&vecB[sub * 8 + 4];
    float x0 = bf2f(xr[0]), x1 = bf2f(xr[1]), x2 = bf2f(xr[2]),
          x3 = bf2f(xr[3]), x4 = bf2f(xr[4]), x5 = bf2f(xr[5]),
          x6 = bf2f(xr[6]), x7 = bf2f(xr[7]);
    edvA = x0 * va0.x + x1 * va0.y + x2 * va0.z + x3 * va0.w + x4 * va1.x +
           x5 * va1.y + x6 * va1.z + x7 * va1.w;
    edvB = x0 * vb0.x + x1 * vb0.y + x2 * vb0.z + x3 * vb0.w + x4 * vb1.x +
           x5 * vb1.y + x6 * vb1.z + x7 * vb1.w;
#pragma unroll
    for (int off = 8; off >= 1; off >>= 1) {
      edvA += __shfl_xor(edvA, off, 16);
      edvB += __shfl_xor(edvB, off, 16);
    }
  }

  float res[8];
#pragma unroll
  for (int j = 0; j < 8; j++) res[j] = 0.f;

#pragma unroll
  for (int half = 0; half < 2; half++) {
    const int* rp = half ? rpB : rpA;
    const ushort* ss = half ? ssB : ssA;
    const float* es = half ? esB : esA;
    const unsigned char* hs = half ? hsB : hsA;
    const float edv = half ? edvB : edvA;
    const int beg = rp[node], end = rp[node + 1];

    float acc[8];
#pragma unroll
    for (int j = 0; j < 8; j++) acc[j] = 0.f;
    float sw = 0.f;

    // single pass: w = exp(relu(es+ed)); acc += w*h; sw += w
    for (int e = beg + slot; e < end; e += 4) {
      int s = ss[e];
      float w = __expf(fmaxf(es[s] + edv, 0.f));
      sw += w;
      uint2 h = *(const uint2*)&hs[(size_t)s * DIM + sub * 8];
      auto p01 = __builtin_amdgcn_cvt_pk_f32_fp8((int)h.x, false);
      auto p23 = __builtin_amdgcn_cvt_pk_f32_fp8((int)h.x, true);
      auto p45 = __builtin_amdgcn_cvt_pk_f32_fp8((int)h.y, false);
      auto p67 = __builtin_amdgcn_cvt_pk_f32_fp8((int)h.y, true);
      acc[0] += w * p01[0]; acc[1] += w * p01[1];
      acc[2] += w * p23[0]; acc[3] += w * p23[1];
      acc[4] += w * p45[0]; acc[5] += w * p45[1];
      acc[6] += w * p67[0]; acc[7] += w * p67[1];
    }

    // combine the 4 slots (lane bits 4,5), then normalize
#pragma unroll
    for (int j = 0; j < 8; j++) {
      acc[j] += __shfl_xor(acc[j], 16, 64);
      acc[j] += __shfl_xor(acc[j], 32, 64);
    }
    sw += __shfl_xor(sw, 16, 64);
    sw += __shfl_xor(sw, 32, 64);
    const float inv = 1.f / fmaxf(sw, 1e-16f);
#pragma unroll
    for (int j = 0; j < 8; j++) res[j] += acc[j] * inv;
  }

  // lane stores dims d, d+1 where d = sub*8 + slot*2 (coalesced 256B row)
  const int d = sub * 8 + slot * 2;
  float2 bb0 = *(const float2*)&b0[d];
  float2 bb1 = *(const float2*)&b1[d];
  float v0 = res[slot * 2] + bb0.x + bb1.x;
  float v1 = res[slot * 2 + 1] + bb0.y + bb1.y;
  ushort2 o; o.x = f2bf(v0); o.y = f2bf(v1);
  *(ushort2*)&outb[(size_t)node * DIM + d] = o;
}

// ---------------------------------------------------------------------------
__global__ __launch_bounds__(256) void colsum_k(
    const ushort* __restrict__ xe, const ushort* __restrict__ xp,
    float* __restrict__ colsum) {
  int tid = blockIdx.x * 256 + threadIdx.x;
  const int stride = 256 * 256;  // multiple of 128 -> fixed column per thread
  float s = 0.f;
  for (int idx = tid; idx < NE_N * DIM; idx += stride) s += bf2f(xe[idx]);
  for (int idx = tid; idx < NP_N * DIM; idx += stride) s += bf2f(xp[idx]);
  __shared__ float ls[256];
  ls[threadIdx.x] = s;
  __syncthreads();
  if (threadIdx.x < 128)
    unsafeAtomicAdd(&colsum[threadIdx.x], ls[threadIdx.x] + ls[threadIdx.x + 128]);
}

// ---------------------------------------------------------------------------
__global__ void final_proj(const float* __restrict__ colsum,
                           const float* __restrict__ lin_W,
                           const float* __restrict__ lin_b,
                           float* __restrict__ out) {
  int j = threadIdx.x;
  if (j >= 2) return;
  float s = 0.f;
#pragma unroll 8
  for (int k = 0; k < DIM; k++) s += colsum[k] * lin_W[k * 2 + j];
  out[j] = s / (float)(NE_N + NP_N) + lin_b[j];
}

// ---------------------------------------------------------------------------
extern "C" void kernel_launch(void* const* d_in, const int* in_sizes, int n_in,
                              void* d_out, int out_size, void* d_ws,
                              size_t ws_size, hipStream_t stream) {
  const float* x_elem  = (const float*)d_in[0];
  const float* x_proc  = (const float*)d_in[1];
  const float* W_src   = (const float*)d_in[2];
  const float* W_dst   = (const float*)d_in[3];
  const float* att_src = (const float*)d_in[4];
  const float* att_dst = (const float*)d_in[5];
  const float* bias    = (const float*)d_in[6];
  const float* lin_W   = (const float*)d_in[7];
  const float* lin_b   = (const float*)d_in[8];
  const int* esrc[4] = {(const int*)d_in[9],  (const int*)d_in[11],
                        (const int*)d_in[13], (const int*)d_in[15]};
  const int* edst[4] = {(const int*)d_in[10], (const int*)d_in[12],
                        (const int*)d_in[14], (const int*)d_in[16]};

  // ---- workspace carve-up (16B-aligned chunks) ----
  char* p = (char*)d_ws;
  ushort* xe_bf[2]; ushort* xp_bf[2];
  xe_bf[0] = (ushort*)p; p += (size_t)NE_N * DIM * 2;
  xe_bf[1] = (ushort*)p; p += (size_t)NE_N * DIM * 2;
  xp_bf[0] = (ushort*)p; p += (size_t)NP_N * DIM * 2;
  xp_bf[1] = (ushort*)p; p += (size_t)NP_N * DIM * 2;
  unsigned char* hsE0 = (unsigned char*)p; p += (size_t)NE_N * DIM;  // W[l,0]
  unsigned char* hsE1 = (unsigned char*)p; p += (size_t)NE_N * DIM;  // W[l,1]
  unsigned char* hsP3 = (unsigned char*)p; p += (size_t)NP_N * DIM;  // W[l,3]
  unsigned char* hsP2 = (unsigned char*)p; p += (size_t)NP_N * DIM;  // W[l,2]
  ushort* WbT = (ushort*)p; p += (size_t)12 * DIM * DIM * 2;
  float* esE0 = (float*)p; p += (size_t)NE_N * 4;
  float* esE1 = (float*)p; p += (size_t)NE_N * 4;
  float* esP3 = (float*)p; p += (size_t)NP_N * 4;
  float* esP2 = (float*)p; p += (size_t)NP_N * 4;
  float* vec = (float*)p; p += 12 * DIM * 4;
  float* csum = (float*)p; p += DIM * 4;
  int* part = (int*)p; p += 4 * 64 * 4;
  int* part_excl = (int*)p; p += 4 * 64 * 4;
  int* cursor[4];
  for (int t = 0; t < 4; t++) { cursor[t] = (int*)p; p += (NE_N + 4) * 4; }
  int* rp[4];
  for (int t = 0; t < 4; t++) { rp[t] = (int*)p; p += (NE_N + 4) * 4; }
  ushort* ssrc[4];
  for (int t = 0; t < 4; t++) { ssrc[t] = (ushort*)p; p += (size_t)E_N * 2; }

  // ---- setup: conversions, vec, CSR ----
  conv_w_k<<<12, 256, 0, stream>>>(W_src, WbT);
  {
    int n4 = (NE_N + NP_N) * DIM / 4;
    conv_x2_k<<<(n4 + 255) / 256, 256, 0, stream>>>(x_elem, x_proc, xe_bf[0],
                                                    xp_bf[0]);
  }
  precompute_vec_k<<<12, 128, 0, stream>>>(W_dst, att_dst, vec);

  hipMemsetAsync(cursor[0], 0, 4 * (NE_N + 4) * sizeof(int), stream);
  hist4_k<<<dim3((E_N + 255) / 256, 4), 256, 0, stream>>>(
      edst[0], edst[1], edst[2], edst[3], cursor[0], cursor[1], cursor[2],
      cursor[3]);
  scanA_k<<<dim3(49, 4), 256, 0, stream>>>(cursor[0], cursor[1], cursor[2],
                                           cursor[3], part);
  scanB_k<<<1, 256, 0, stream>>>(part, part_excl, rp[0], rp[1], rp[2], rp[3]);
  scanC_k<<<dim3(49, 4), 256, 0, stream>>>(cursor[0], cursor[1], cursor[2],
                                           cursor[3], rp[0], rp[1], rp[2],
                                           rp[3], cursor[0], cursor[1],
                                           cursor[2], cursor[3], part_excl);
  fill4_k<<<dim3((E_N + 255) / 256, 4), 256, 0, stream>>>(
      esrc[0], esrc[1], esrc[2], esrc[3], edst[0], edst[1], edst[2], edst[3],
      cursor[0], cursor[1], cursor[2], cursor[3], ssrc[0], ssrc[1], ssrc[2],
      ssrc[3]);

  // ---- layers: 2 dispatches each ----
  int c = 0;
  for (int l = 0; l < 3; l++) {
    gemm_dual2<<<EBLK + PBLK, 256, 0, stream>>>(
        xe_bf[c], xp_bf[c], WbT, att_src, l, hsE0, hsE1, hsP3, hsP2, esE0,
        esE1, esP3, esP2);
    gat_gather_all<<<(NE_N + NP_N) / 4, 256, 0, stream>>>(
        rp[0], ssrc[0], rp[1], ssrc[1], rp[2], ssrc[2], rp[3], ssrc[3], esE0,
        hsE0, esE1, hsE1, esP3, hsP3, esP2, hsP2, xe_bf[c], xp_bf[c], vec,
        bias, l, xe_bf[1 - c], xp_bf[1 - c]);
    c = 1 - c;
  }

  hipMemsetAsync(csum, 0, DIM * sizeof(float), stream);
  colsum_k<<<256, 256, 0, stream>>>(xe_bf[c], xp_bf[c], csum);
  final_proj<<<1, 64, 0, stream>>>(csum, lin_W, lin_b, (float*)d_out);
}

// Round 7
// 564.953 us; speedup vs baseline: 8.9642x; 1.0776x over previous
//
#include <hip/hip_runtime.h>

#define NE_N 50000
#define NP_N 25000
#define E_N 200000
#define DIM 128

typedef __attribute__((ext_vector_type(8))) short short8;
typedef __attribute__((ext_vector_type(8))) ushort ushort8;
typedef __attribute__((ext_vector_type(4))) float f32x4;

static __device__ __forceinline__ ushort f2bf(float f) {
  unsigned x = __float_as_uint(f);
  return (ushort)((x + 0x7fffu + ((x >> 16) & 1u)) >> 16);  // RNE
}
static __device__ __forceinline__ float bf2f(ushort u) {
  return __uint_as_float(((unsigned)u) << 16);
}

// ---------------------------------------------------------------------------
// W_src [12][128][128] fp32 -> WbT [12][n][k] bf16 (transposed per matrix)
__global__ __launch_bounds__(256) void conv_w_k(const float* __restrict__ W,
                                                ushort* __restrict__ WbT) {
  int lt = blockIdx.x;
  const float* src = W + (size_t)lt * DIM * DIM;
  ushort* dst = WbT + (size_t)lt * DIM * DIM;
  for (int i = threadIdx.x; i < DIM * DIM; i += 256) {
    int k = i >> 7, n = i & 127;
    dst[n * DIM + k] = f2bf(src[i]);
  }
}

// fp32 -> bf16 for both feature matrices in one dispatch
__global__ __launch_bounds__(256) void conv_x2_k(const float* __restrict__ xe,
                                                 const float* __restrict__ xp,
                                                 ushort* __restrict__ xeb,
                                                 ushort* __restrict__ xpb) {
  const int n4e = NE_N * DIM / 4;
  const int n4p = NP_N * DIM / 4;
  int i = blockIdx.x * 256 + threadIdx.x;
  const float* x;
  ushort* xb;
  if (i < n4e) {
    x = xe; xb = xeb;
  } else {
    i -= n4e;
    if (i >= n4p) return;
    x = xp; xb = xpb;
  }
  float4 v = *(const float4*)&x[(size_t)i * 4];
  ushort4 o;
  o.x = f2bf(v.x); o.y = f2bf(v.y); o.z = f2bf(v.z); o.w = f2bf(v.w);
  *(ushort4*)&xb[(size_t)i * 4] = o;
}

// ---------------------------------------------------------------------------
// vec[lt][i] = sum_j W_dst[lt][i][j] * att_dst[lt][j]  (fp32, full precision)
__global__ __launch_bounds__(128) void precompute_vec_k(
    const float* __restrict__ W_dst, const float* __restrict__ att_dst,
    float* __restrict__ vec) {
  int lt = blockIdx.x;
  int i = threadIdx.x;
  const float* Wd = W_dst + (size_t)lt * DIM * DIM;
  const float* ad = att_dst + lt * DIM;
  float s = 0.f;
#pragma unroll 8
  for (int j = 0; j < DIM; j++) s += Wd[i * DIM + j] * ad[j];
  vec[lt * DIM + i] = s;
}

// ---------------------------------------------------------------------------
// CSR build: fused histogram over 4 edge types (grid.y = type)
__global__ __launch_bounds__(256) void hist4_k(
    const int* __restrict__ d0, const int* __restrict__ d1,
    const int* __restrict__ d2, const int* __restrict__ d3,
    int* __restrict__ c0, int* __restrict__ c1, int* __restrict__ c2,
    int* __restrict__ c3) {
  int ty = blockIdx.y;
  const int* dst = ty == 0 ? d0 : ty == 1 ? d1 : ty == 2 ? d2 : d3;
  int* cnt = ty == 0 ? c0 : ty == 1 ? c1 : ty == 2 ? c2 : c3;
  int e = blockIdx.x * 256 + threadIdx.x;
  if (e < E_N) atomicAdd(&cnt[dst[e]], 1);
}

// phase A: per-1024-block sums. grid (49, 4)
__global__ __launch_bounds__(256) void scanA_k(
    const int* __restrict__ c0, const int* __restrict__ c1,
    const int* __restrict__ c2, const int* __restrict__ c3,
    int* __restrict__ part) {
  int ty = blockIdx.y;
  const int* cnt = ty == 0 ? c0 : ty == 1 ? c1 : ty == 2 ? c2 : c3;
  int n = (ty == 0 || ty == 3) ? NE_N : NP_N;
  int nblk = (n + 1023) >> 10;
  if ((int)blockIdx.x >= nblk) return;
  int base = blockIdx.x * 1024 + threadIdx.x * 4;
  int s = 0;
#pragma unroll
  for (int j = 0; j < 4; j++) s += (base + j < n) ? cnt[base + j] : 0;
  int lane = threadIdx.x & 63, wid = threadIdx.x >> 6;
#pragma unroll
  for (int off = 32; off > 0; off >>= 1) s += __shfl_xor(s, off, 64);
  __shared__ int ws4[4];
  if (lane == 0) ws4[wid] = s;
  __syncthreads();
  if (threadIdx.x == 0)
    part[ty * 64 + blockIdx.x] = ws4[0] + ws4[1] + ws4[2] + ws4[3];
}

// phase B: scan partials (<=49/type), 1 block, wave w = type w
__global__ __launch_bounds__(256) void scanB_k(
    const int* __restrict__ part, int* __restrict__ part_excl,
    int* __restrict__ r0, int* __restrict__ r1, int* __restrict__ r2,
    int* __restrict__ r3) {
  int ty = threadIdx.x >> 6, lane = threadIdx.x & 63;
  int n = (ty == 0 || ty == 3) ? NE_N : NP_N;
  int nblk = (n + 1023) >> 10;
  int v = (lane < nblk) ? part[ty * 64 + lane] : 0;
  int sc = v;
#pragma unroll
  for (int off = 1; off < 64; off <<= 1) {
    int t = __shfl_up(sc, off, 64);
    if (lane >= off) sc += t;
  }
  if (lane < nblk) part_excl[ty * 64 + lane] = sc - v;
  if (lane == nblk - 1) {
    int* rp = ty == 0 ? r0 : ty == 1 ? r1 : ty == 2 ? r2 : r3;
    rp[n] = sc;  // total
  }
}

// phase C: write exclusive scan to rp + cursor. grid (49, 4)
__global__ __launch_bounds__(256) void scanC_k(
    const int* __restrict__ c0, const int* __restrict__ c1,
    const int* __restrict__ c2, const int* __restrict__ c3,
    int* __restrict__ r0, int* __restrict__ r1, int* __restrict__ r2,
    int* __restrict__ r3, int* __restrict__ u0, int* __restrict__ u1,
    int* __restrict__ u2, int* __restrict__ u3,
    const int* __restrict__ part_excl) {
  int ty = blockIdx.y;
  const int* cnt = ty == 0 ? c0 : ty == 1 ? c1 : ty == 2 ? c2 : c3;
  int* rp = ty == 0 ? r0 : ty == 1 ? r1 : ty == 2 ? r2 : r3;
  int* cur = ty == 0 ? u0 : ty == 1 ? u1 : ty == 2 ? u2 : u3;
  int n = (ty == 0 || ty == 3) ? NE_N : NP_N;
  int nblk = (n + 1023) >> 10;
  if ((int)blockIdx.x >= nblk) return;
  int base = blockIdx.x * 1024 + threadIdx.x * 4;
  int v[4];
#pragma unroll
  for (int j = 0; j < 4; j++) v[j] = (base + j < n) ? cnt[base + j] : 0;
  int s = v[0] + v[1] + v[2] + v[3];
  int lane = threadIdx.x & 63, wid = threadIdx.x >> 6;
  int sc = s;
#pragma unroll
  for (int off = 1; off < 64; off <<= 1) {
    int t = __shfl_up(sc, off, 64);
    if (lane >= off) sc += t;
  }
  __shared__ int ws4[4];
  if (lane == 63) ws4[wid] = sc;
  __syncthreads();
  int wbase = 0;
  for (int w = 0; w < wid; w++) wbase += ws4[w];
  int p = part_excl[ty * 64 + blockIdx.x] + wbase + sc - s;
#pragma unroll
  for (int j = 0; j < 4; j++) {
    if (base + j < n) { rp[base + j] = p; cur[base + j] = p; }
    p += v[j];
  }
}

// fused fill over 4 types (grid.y = type); ssrc stored as ushort (ids < 64K)
__global__ __launch_bounds__(256) void fill4_k(
    const int* __restrict__ s0, const int* __restrict__ s1,
    const int* __restrict__ s2, const int* __restrict__ s3,
    const int* __restrict__ d0, const int* __restrict__ d1,
    const int* __restrict__ d2, const int* __restrict__ d3,
    int* __restrict__ u0, int* __restrict__ u1, int* __restrict__ u2,
    int* __restrict__ u3, ushort* __restrict__ o0, ushort* __restrict__ o1,
    ushort* __restrict__ o2, ushort* __restrict__ o3) {
  int ty = blockIdx.y;
  const int* src = ty == 0 ? s0 : ty == 1 ? s1 : ty == 2 ? s2 : s3;
  const int* dst = ty == 0 ? d0 : ty == 1 ? d1 : ty == 2 ? d2 : d3;
  int* cur = ty == 0 ? u0 : ty == 1 ? u1 : ty == 2 ? u2 : u3;
  ushort* out = ty == 0 ? o0 : ty == 1 ? o1 : ty == 2 ? o2 : o3;
  int e = blockIdx.x * 256 + threadIdx.x;
  if (e < E_N) {
    int pos = atomicAdd(&cur[dst[e]], 1);
    out[pos] = (ushort)src[e];
  }
}

// ---------------------------------------------------------------------------
// Combined dual MFMA GEMM for both source types in one dispatch.
// OPERANDS SWAPPED: mfma(w_frag, x_frag) so lane (m,quad) holds 4 CONSECUTIVE
// output cols [f*16+quad*4, +4) of x-row (row0+m) -> fp8 pack is lane-local
// (no shuffles) and stores are fully-active dwords. Loads are identical to
// the unswapped version (A/B fragment layouts are symmetric).
#define EBLK ((NE_N + 63) / 64)
#define PBLK ((NP_N + 63) / 64)
__global__ __launch_bounds__(256) void gemm_dual2(
    const ushort* __restrict__ xe, const ushort* __restrict__ xp,
    const ushort* __restrict__ WbT, const float* __restrict__ att, int l,
    unsigned char* __restrict__ hsE0, unsigned char* __restrict__ hsE1,
    unsigned char* __restrict__ hsP3, unsigned char* __restrict__ hsP2,
    float* __restrict__ esE0, float* __restrict__ esE1,
    float* __restrict__ esP3, float* __restrict__ esP2) {
  int blk = blockIdx.x;
  const ushort* xb;
  const ushort *W0T, *W1T;
  const float *a0, *a1;
  unsigned char *hs0, *hs1;
  float *es0, *es1;
  int N;
  if (blk < EBLK) {
    xb = xe; N = NE_N;
    W0T = WbT + (size_t)(l * 4 + 0) * DIM * DIM;
    W1T = WbT + (size_t)(l * 4 + 1) * DIM * DIM;
    a0 = att + (l * 4 + 0) * DIM; a1 = att + (l * 4 + 1) * DIM;
    hs0 = hsE0; hs1 = hsE1; es0 = esE0; es1 = esE1;
  } else {
    blk -= EBLK; xb = xp; N = NP_N;
    W0T = WbT + (size_t)(l * 4 + 3) * DIM * DIM;
    W1T = WbT + (size_t)(l * 4 + 2) * DIM * DIM;
    a0 = att + (l * 4 + 3) * DIM; a1 = att + (l * 4 + 2) * DIM;
    hs0 = hsP3; hs1 = hsP2; es0 = esP3; es1 = esP2;
  }

  const int wave = threadIdx.x >> 6;
  const int lane = threadIdx.x & 63;
  const int m = lane & 15, quad = lane >> 4;
  const int row0 = blk * 64 + wave * 16;
  if (row0 >= N) return;
  int rowA = row0 + m;
  if (rowA >= N) rowA = N - 1;  // clamp loads; stores guarded

  f32x4 acc0[8], acc1[8];
#pragma unroll
  for (int f = 0; f < 8; f++) {
    acc0[f] = (f32x4){0.f, 0.f, 0.f, 0.f};
    acc1[f] = (f32x4){0.f, 0.f, 0.f, 0.f};
  }

  const short8* xpr = (const short8*)(xb + (size_t)rowA * DIM + quad * 8);
#pragma unroll
  for (int k0 = 0; k0 < 4; k0++) {
    short8 xv = xpr[k0 * 4];  // x[rowA][k0*32 + quad*8 .. +7]
#pragma unroll
    for (int f = 0; f < 8; f++) {
      size_t boff = (size_t)(f * 16 + m) * DIM + k0 * 32 + quad * 8;
      short8 w0 = *(const short8*)(W0T + boff);
      acc0[f] = __builtin_amdgcn_mfma_f32_16x16x32_bf16(w0, xv, acc0[f], 0, 0, 0);
      short8 w1 = *(const short8*)(W1T + boff);
      acc1[f] = __builtin_amdgcn_mfma_f32_16x16x32_bf16(w1, xv, acc1[f], 0, 0, 0);
    }
  }

  // lane (m,quad) holds outcols f*16+quad*4+{0..3} of x-row (row0+m)
  const int row = row0 + m;
#pragma unroll
  for (int set = 0; set < 2; set++) {
    f32x4* acc = set ? acc1 : acc0;
    const float* as = set ? a1 : a0;
    float* es = set ? es1 : es0;
    unsigned char* hs = set ? hs1 : hs0;

    // es: lane-local partial dot, reduce over quad (2 shuffles), coalesced
    float esum = 0.f;
#pragma unroll
    for (int f = 0; f < 8; f++) {
      float4 av = *(const float4*)&as[f * 16 + quad * 4];
      esum += acc[f][0] * av.x + acc[f][1] * av.y + acc[f][2] * av.z +
              acc[f][3] * av.w;
    }
    esum += __shfl_xor(esum, 16, 64);
    esum += __shfl_xor(esum, 32, 64);
    if (quad == 0 && row < N) es[row] = esum;

    // hs fp8: pack 4 local cols into one dword, fully-active store
    if (row < N) {
#pragma unroll
      for (int f = 0; f < 8; f++) {
        int w = __builtin_amdgcn_cvt_pk_fp8_f32(acc[f][0], acc[f][1], 0, false);
        w = __builtin_amdgcn_cvt_pk_fp8_f32(acc[f][2], acc[f][3], w, true);
        *(unsigned*)&hs[(size_t)row * DIM + f * 16 + quad * 4] = (unsigned)w;
      }
    }
  }
}

// ---------------------------------------------------------------------------
// Combined dual-type gather for both dst types in one dispatch.
// Single-pass softmax (logits >= 0, O(10): exp can't overflow fp32).
// hs is fp8 e4m3; ssrc is ushort. One 64-lane wave per dst node:
// 4 edge-slots x 16 sublanes; sublane reads 8B (8 fp8) of the 128B row.
__global__ __launch_bounds__(256) void gat_gather_all(
    const int* __restrict__ rp0, const ushort* __restrict__ ss0,
    const int* __restrict__ rp1, const ushort* __restrict__ ss1,
    const int* __restrict__ rp2, const ushort* __restrict__ ss2,
    const int* __restrict__ rp3, const ushort* __restrict__ ss3,
    const float* __restrict__ esE0, const unsigned char* __restrict__ hsE0,
    const float* __restrict__ esE1, const unsigned char* __restrict__ hsE1,
    const float* __restrict__ esP3, const unsigned char* __restrict__ hsP3,
    const float* __restrict__ esP2, const unsigned char* __restrict__ hsP2,
    const ushort* __restrict__ xe, const ushort* __restrict__ xp,
    const float* __restrict__ vec, const float* __restrict__ bias, int l,
    ushort* __restrict__ outxe, ushort* __restrict__ outxp) {
  const int wid = (blockIdx.x * 256 + threadIdx.x) >> 6;
  const int lane = threadIdx.x & 63;
  const int slot = lane >> 4, sub = lane & 15;

  int node;
  const int *rpA, *rpB;
  const ushort *ssA, *ssB;
  const float *esA, *esB;
  const unsigned char *hsA, *hsB;
  const ushort* xd;
  const float *vecA, *vecB, *b0, *b1;
  ushort* outb;
  if (wid < NE_N) {  // e-dst: ee (A) + pe (B)
    node = wid;
    rpA = rp0; ssA = ss0; esA = esE0; hsA = hsE0;
    rpB = rp3; ssB = ss3; esB = esP3; hsB = hsP3;
    xd = xe;
    vecA = vec + (l * 4 + 0) * DIM; vecB = vec + (l * 4 + 3) * DIM;
    b0 = bias + (l * 4 + 0) * DIM; b1 = bias + (l * 4 + 3) * DIM;
    outb = outxe;
  } else if (wid < NE_N + NP_N) {  // p-dst: ep (A) + pp (B)
    node = wid - NE_N;
    rpA = rp1; ssA = ss1; esA = esE1; hsA = hsE1;
    rpB = rp2; ssB = ss2; esB = esP2; hsB = hsP2;
    xd = xp;
    vecA = vec + (l * 4 + 1) * DIM; vecB = vec + (l * 4 + 2) * DIM;
    b0 = bias + (l * 4 + 1) * DIM; b1 = bias + (l * 4 + 2) * DIM;
    outb = outxp;
  } else {
    return;
  }

  // ed for both halves: dot(xd[node], vec{A,B}) — reduce over 16 sublanes
  float edvA = 0.f, edvB = 0.f;
  {
    ushort8 xr = *(const ushort8*)&xd[(size_t)node * DIM + sub * 8];
    float4 va0 = *(const float4*)&vecA[sub * 8];
    float4 va1 = *(const float4*)&vecA[sub * 8 + 4];
    float4 vb0 = *(const float4*)&vecB[sub * 8];
    float4 vb1 = *(const float4*)&vecB[sub * 8 + 4];
    float x0 = bf2f(xr[0]), x1 = bf2f(xr[1]), x2 = bf2f(xr[2]),
          x3 = bf2f(xr[3]), x4 = bf2f(xr[4]), x5 = bf2f(xr[5]),
          x6 = bf2f(xr[6]), x7 = bf2f(xr[7]);
    edvA = x0 * va0.x + x1 * va0.y + x2 * va0.z + x3 * va0.w + x4 * va1.x +
           x5 * va1.y + x6 * va1.z + x7 * va1.w;
    edvB = x0 * vb0.x + x1 * vb0.y + x2 * vb0.z + x3 * vb0.w + x4 * vb1.x +
           x5 * vb1.y + x6 * vb1.z + x7 * vb1.w;
#pragma unroll
    for (int off = 8; off >= 1; off >>= 1) {
      edvA += __shfl_xor(edvA, off, 16);
      edvB += __shfl_xor(edvB, off, 16);
    }
  }

  float res[8];
#pragma unroll
  for (int j = 0; j < 8; j++) res[j] = 0.f;

#pragma unroll
  for (int half = 0; half < 2; half++) {
    const int* rp = half ? rpB : rpA;
    const ushort* ss = half ? ssB : ssA;
    const float* es = half ? esB : esA;
    const unsigned char* hs = half ? hsB : hsA;
    const float edv = half ? edvB : edvA;
    const int beg = rp[node], end = rp[node + 1];

    float acc[8];
#pragma unroll
    for (int j = 0; j < 8; j++) acc[j] = 0.f;
    float sw = 0.f;

    // single pass: w = exp(relu(es+ed)); acc += w*h; sw += w
    for (int e = beg + slot; e < end; e += 4) {
      int s = ss[e];
      float w = __expf(fmaxf(es[s] + edv, 0.f));
      sw += w;
      uint2 h = *(const uint2*)&hs[(size_t)s * DIM + sub * 8];
      auto p01 = __builtin_amdgcn_cvt_pk_f32_fp8((int)h.x, false);
      auto p23 = __builtin_amdgcn_cvt_pk_f32_fp8((int)h.x, true);
      auto p45 = __builtin_amdgcn_cvt_pk_f32_fp8((int)h.y, false);
      auto p67 = __builtin_amdgcn_cvt_pk_f32_fp8((int)h.y, true);
      acc[0] += w * p01[0]; acc[1] += w * p01[1];
      acc[2] += w * p23[0]; acc[3] += w * p23[1];
      acc[4] += w * p45[0]; acc[5] += w * p45[1];
      acc[6] += w * p67[0]; acc[7] += w * p67[1];
    }

    // combine the 4 slots (lane bits 4,5), then normalize
#pragma unroll
    for (int j = 0; j < 8; j++) {
      acc[j] += __shfl_xor(acc[j], 16, 64);
      acc[j] += __shfl_xor(acc[j], 32, 64);
    }
    sw += __shfl_xor(sw, 16, 64);
    sw += __shfl_xor(sw, 32, 64);
    const float inv = 1.f / fmaxf(sw, 1e-16f);
#pragma unroll
    for (int j = 0; j < 8; j++) res[j] += acc[j] * inv;
  }

  // lane stores dims d, d+1 where d = sub*8 + slot*2 (coalesced 256B row)
  const int d = sub * 8 + slot * 2;
  float2 bb0 = *(const float2*)&b0[d];
  float2 bb1 = *(const float2*)&b1[d];
  float v0 = res[slot * 2] + bb0.x + bb1.x;
  float v1 = res[slot * 2 + 1] + bb0.y + bb1.y;
  ushort2 o; o.x = f2bf(v0); o.y = f2bf(v1);
  *(ushort2*)&outb[(size_t)node * DIM + d] = o;
}

// ---------------------------------------------------------------------------
__global__ __launch_bounds__(256) void colsum_k(
    const ushort* __restrict__ xe, const ushort* __restrict__ xp,
    float* __restrict__ colsum) {
  int tid = blockIdx.x * 256 + threadIdx.x;
  const int stride = 256 * 256;  // multiple of 128 -> fixed column per thread
  float s = 0.f;
  for (int idx = tid; idx < NE_N * DIM; idx += stride) s += bf2f(xe[idx]);
  for (int idx = tid; idx < NP_N * DIM; idx += stride) s += bf2f(xp[idx]);
  __shared__ float ls[256];
  ls[threadIdx.x] = s;
  __syncthreads();
  if (threadIdx.x < 128)
    unsafeAtomicAdd(&colsum[threadIdx.x], ls[threadIdx.x] + ls[threadIdx.x + 128]);
}

// ---------------------------------------------------------------------------
__global__ void final_proj(const float* __restrict__ colsum,
                           const float* __restrict__ lin_W,
                           const float* __restrict__ lin_b,
                           float* __restrict__ out) {
  int j = threadIdx.x;
  if (j >= 2) return;
  float s = 0.f;
#pragma unroll 8
  for (int k = 0; k < DIM; k++) s += colsum[k] * lin_W[k * 2 + j];
  out[j] = s / (float)(NE_N + NP_N) + lin_b[j];
}

// ---------------------------------------------------------------------------
extern "C" void kernel_launch(void* const* d_in, const int* in_sizes, int n_in,
                              void* d_out, int out_size, void* d_ws,
                              size_t ws_size, hipStream_t stream) {
  const float* x_elem  = (const float*)d_in[0];
  const float* x_proc  = (const float*)d_in[1];
  const float* W_src   = (const float*)d_in[2];
  const float* W_dst   = (const float*)d_in[3];
  const float* att_src = (const float*)d_in[4];
  const float* att_dst = (const float*)d_in[5];
  const float* bias    = (const float*)d_in[6];
  const float* lin_W   = (const float*)d_in[7];
  const float* lin_b   = (const float*)d_in[8];
  const int* esrc[4] = {(const int*)d_in[9],  (const int*)d_in[11],
                        (const int*)d_in[13], (const int*)d_in[15]};
  const int* edst[4] = {(const int*)d_in[10], (const int*)d_in[12],
                        (const int*)d_in[14], (const int*)d_in[16]};

  // ---- workspace carve-up (16B-aligned chunks) ----
  char* p = (char*)d_ws;
  ushort* xe_bf[2]; ushort* xp_bf[2];
  xe_bf[0] = (ushort*)p; p += (size_t)NE_N * DIM * 2;
  xe_bf[1] = (ushort*)p; p += (size_t)NE_N * DIM * 2;
  xp_bf[0] = (ushort*)p; p += (size_t)NP_N * DIM * 2;
  xp_bf[1] = (ushort*)p; p += (size_t)NP_N * DIM * 2;
  unsigned char* hsE0 = (unsigned char*)p; p += (size_t)NE_N * DIM;  // W[l,0]
  unsigned char* hsE1 = (unsigned char*)p; p += (size_t)NE_N * DIM;  // W[l,1]
  unsigned char* hsP3 = (unsigned char*)p; p += (size_t)NP_N * DIM;  // W[l,3]
  unsigned char* hsP2 = (unsigned char*)p; p += (size_t)NP_N * DIM;  // W[l,2]
  ushort* WbT = (ushort*)p; p += (size_t)12 * DIM * DIM * 2;
  float* esE0 = (float*)p; p += (size_t)NE_N * 4;
  float* esE1 = (float*)p; p += (size_t)NE_N * 4;
  float* esP3 = (float*)p; p += (size_t)NP_N * 4;
  float* esP2 = (float*)p; p += (size_t)NP_N * 4;
  float* vec = (float*)p; p += 12 * DIM * 4;
  float* csum = (float*)p; p += DIM * 4;
  int* part = (int*)p; p += 4 * 64 * 4;
  int* part_excl = (int*)p; p += 4 * 64 * 4;
  int* cursor[4];
  for (int t = 0; t < 4; t++) { cursor[t] = (int*)p; p += (NE_N + 4) * 4; }
  int* rp[4];
  for (int t = 0; t < 4; t++) { rp[t] = (int*)p; p += (NE_N + 4) * 4; }
  ushort* ssrc[4];
  for (int t = 0; t < 4; t++) { ssrc[t] = (ushort*)p; p += (size_t)E_N * 2; }

  // ---- setup: conversions, vec, CSR ----
  conv_w_k<<<12, 256, 0, stream>>>(W_src, WbT);
  {
    int n4 = (NE_N + NP_N) * DIM / 4;
    conv_x2_k<<<(n4 + 255) / 256, 256, 0, stream>>>(x_elem, x_proc, xe_bf[0],
                                                    xp_bf[0]);
  }
  precompute_vec_k<<<12, 128, 0, stream>>>(W_dst, att_dst, vec);

  hipMemsetAsync(cursor[0], 0, 4 * (NE_N + 4) * sizeof(int), stream);
  hist4_k<<<dim3((E_N + 255) / 256, 4), 256, 0, stream>>>(
      edst[0], edst[1], edst[2], edst[3], cursor[0], cursor[1], cursor[2],
      cursor[3]);
  scanA_k<<<dim3(49, 4), 256, 0, stream>>>(cursor[0], cursor[1], cursor[2],
                                           cursor[3], part);
  scanB_k<<<1, 256, 0, stream>>>(part, part_excl, rp[0], rp[1], rp[2], rp[3]);
  scanC_k<<<dim3(49, 4), 256, 0, stream>>>(cursor[0], cursor[1], cursor[2],
                                           cursor[3], rp[0], rp[1], rp[2],
                                           rp[3], cursor[0], cursor[1],
                                           cursor[2], cursor[3], part_excl);
  fill4_k<<<dim3((E_N + 255) / 256, 4), 256, 0, stream>>>(
      esrc[0], esrc[1], esrc[2], esrc[3], edst[0], edst[1], edst[2], edst[3],
      cursor[0], cursor[1], cursor[2], cursor[3], ssrc[0], ssrc[1], ssrc[2],
      ssrc[3]);

  // ---- layers: 2 dispatches each ----
  int c = 0;
  for (int l = 0; l < 3; l++) {
    gemm_dual2<<<EBLK + PBLK, 256, 0, stream>>>(
        xe_bf[c], xp_bf[c], WbT, att_src, l, hsE0, hsE1, hsP3, hsP2, esE0,
        esE1, esP3, esP2);
    gat_gather_all<<<(NE_N + NP_N) / 4, 256, 0, stream>>>(
        rp[0], ssrc[0], rp[1], ssrc[1], rp[2], ssrc[2], rp[3], ssrc[3], esE0,
        hsE0, esE1, hsE1, esP3, hsP3, esP2, hsP2, xe_bf[c], xp_bf[c], vec,
        bias, l, xe_bf[1 - c], xp_bf[1 - c]);
    c = 1 - c;
  }

  hipMemsetAsync(csum, 0, DIM * sizeof(float), stream);
  colsum_k<<<256, 256, 0, stream>>>(xe_bf[c], xp_bf[c], csum);
  final_proj<<<1, 64, 0, stream>>>(csum, lin_W, lin_b, (float*)d_out);
}

// Round 8
// 519.688 us; speedup vs baseline: 9.7450x; 1.0871x over previous
//
#include <hip/hip_runtime.h>

#define NE_N 50000
#define NP_N 25000
#define E_N 200000
#define DIM 128
#define LOG2E 1.4426950408889634f

typedef __attribute__((ext_vector_type(8))) short short8;
typedef __attribute__((ext_vector_type(8))) ushort ushort8;
typedef __attribute__((ext_vector_type(4))) float f32x4;

static __device__ __forceinline__ ushort f2bf(float f) {
  unsigned x = __float_as_uint(f);
  return (ushort)((x + 0x7fffu + ((x >> 16) & 1u)) >> 16);  // RNE
}
static __device__ __forceinline__ float bf2f(ushort u) {
  return __uint_as_float(((unsigned)u) << 16);
}

// ---------------------------------------------------------------------------
// Fused setup: conv_w (12 blk) | conv_x (9375 blk) | vec (6 blk) |
// hist (3128 blk). All independent; co-resident to overlap atomic latency
// with conversion bandwidth.
#define SU_CW 12
#define SU_CX 9375
#define SU_V 6
#define SU_H 3128
__global__ __launch_bounds__(256) void setup_fused(
    const float* __restrict__ W_src, const float* __restrict__ x_elem,
    const float* __restrict__ x_proc, const float* __restrict__ W_dst,
    const float* __restrict__ att_dst, ushort* __restrict__ WbT,
    ushort* __restrict__ xeb, ushort* __restrict__ xpb,
    float* __restrict__ vec, const int* __restrict__ d0,
    const int* __restrict__ d1, const int* __restrict__ d2,
    const int* __restrict__ d3, int* __restrict__ c0, int* __restrict__ c1,
    int* __restrict__ c2, int* __restrict__ c3) {
  int blk = blockIdx.x;
  int tid = threadIdx.x;
  if (blk < SU_CW) {
    // W transpose->bf16
    const float* src = W_src + (size_t)blk * DIM * DIM;
    ushort* dst = WbT + (size_t)blk * DIM * DIM;
    for (int i = tid; i < DIM * DIM; i += 256) {
      int k = i >> 7, n = i & 127;
      dst[n * DIM + k] = f2bf(src[i]);
    }
  } else if (blk < SU_CW + SU_CX) {
    // x fp32->bf16 (float4 granularity)
    const int n4e = NE_N * DIM / 4;
    const int n4p = NP_N * DIM / 4;
    int i = (blk - SU_CW) * 256 + tid;
    const float* x;
    ushort* xb;
    if (i < n4e) {
      x = x_elem; xb = xeb;
    } else {
      i -= n4e;
      if (i >= n4p) return;
      x = x_proc; xb = xpb;
    }
    float4 v = *(const float4*)&x[(size_t)i * 4];
    ushort4 o;
    o.x = f2bf(v.x); o.y = f2bf(v.y); o.z = f2bf(v.z); o.w = f2bf(v.w);
    *(ushort4*)&xb[(size_t)i * 4] = o;
  } else if (blk < SU_CW + SU_CX + SU_V) {
    // vec[lt] = W_dst[lt] @ att_dst[lt]
    int b = blk - SU_CW - SU_CX;
    int lt = b * 2 + (tid >> 7);
    int i = tid & 127;
    const float* Wd = W_dst + (size_t)lt * DIM * DIM;
    const float* ad = att_dst + lt * DIM;
    float s = 0.f;
#pragma unroll 8
    for (int j = 0; j < DIM; j++) s += Wd[i * DIM + j] * ad[j];
    vec[lt * DIM + i] = s;
  } else {
    // histogram of dst per type
    int b = blk - SU_CW - SU_CX - SU_V;
    int ty = b / 782;
    int e = (b % 782) * 256 + tid;
    if (e >= E_N) return;
    const int* dst = ty == 0 ? d0 : ty == 1 ? d1 : ty == 2 ? d2 : d3;
    int* cnt = ty == 0 ? c0 : ty == 1 ? c1 : ty == 2 ? c2 : c3;
    atomicAdd(&cnt[dst[e]], 1);
  }
}

// ---------------------------------------------------------------------------
// phase A: per-1024-block sums. grid (49, 4)
__global__ __launch_bounds__(256) void scanA_k(
    const int* __restrict__ c0, const int* __restrict__ c1,
    const int* __restrict__ c2, const int* __restrict__ c3,
    int* __restrict__ part) {
  int ty = blockIdx.y;
  const int* cnt = ty == 0 ? c0 : ty == 1 ? c1 : ty == 2 ? c2 : c3;
  int n = (ty == 0 || ty == 3) ? NE_N : NP_N;
  int nblk = (n + 1023) >> 10;
  if ((int)blockIdx.x >= nblk) return;
  int base = blockIdx.x * 1024 + threadIdx.x * 4;
  int s = 0;
#pragma unroll
  for (int j = 0; j < 4; j++) s += (base + j < n) ? cnt[base + j] : 0;
  int lane = threadIdx.x & 63, wid = threadIdx.x >> 6;
#pragma unroll
  for (int off = 32; off > 0; off >>= 1) s += __shfl_xor(s, off, 64);
  __shared__ int ws4[4];
  if (lane == 0) ws4[wid] = s;
  __syncthreads();
  if (threadIdx.x == 0)
    part[ty * 64 + blockIdx.x] = ws4[0] + ws4[1] + ws4[2] + ws4[3];
}

// phase B: scan partials (<=49/type), 1 block, wave w = type w
__global__ __launch_bounds__(256) void scanB_k(
    const int* __restrict__ part, int* __restrict__ part_excl,
    int* __restrict__ r0, int* __restrict__ r1, int* __restrict__ r2,
    int* __restrict__ r3) {
  int ty = threadIdx.x >> 6, lane = threadIdx.x & 63;
  int n = (ty == 0 || ty == 3) ? NE_N : NP_N;
  int nblk = (n + 1023) >> 10;
  int v = (lane < nblk) ? part[ty * 64 + lane] : 0;
  int sc = v;
#pragma unroll
  for (int off = 1; off < 64; off <<= 1) {
    int t = __shfl_up(sc, off, 64);
    if (lane >= off) sc += t;
  }
  if (lane < nblk) part_excl[ty * 64 + lane] = sc - v;
  if (lane == nblk - 1) {
    int* rp = ty == 0 ? r0 : ty == 1 ? r1 : ty == 2 ? r2 : r3;
    rp[n] = sc;  // total
  }
}

// phase C: write exclusive scan to rp + cursor. grid (49, 4)
__global__ __launch_bounds__(256) void scanC_k(
    const int* __restrict__ c0, const int* __restrict__ c1,
    const int* __restrict__ c2, const int* __restrict__ c3,
    int* __restrict__ r0, int* __restrict__ r1, int* __restrict__ r2,
    int* __restrict__ r3, int* __restrict__ u0, int* __restrict__ u1,
    int* __restrict__ u2, int* __restrict__ u3,
    const int* __restrict__ part_excl) {
  int ty = blockIdx.y;
  const int* cnt = ty == 0 ? c0 : ty == 1 ? c1 : ty == 2 ? c2 : c3;
  int* rp = ty == 0 ? r0 : ty == 1 ? r1 : ty == 2 ? r2 : r3;
  int* cur = ty == 0 ? u0 : ty == 1 ? u1 : ty == 2 ? u2 : u3;
  int n = (ty == 0 || ty == 3) ? NE_N : NP_N;
  int nblk = (n + 1023) >> 10;
  if ((int)blockIdx.x >= nblk) return;
  int base = blockIdx.x * 1024 + threadIdx.x * 4;
  int v[4];
#pragma unroll
  for (int j = 0; j < 4; j++) v[j] = (base + j < n) ? cnt[base + j] : 0;
  int s = v[0] + v[1] + v[2] + v[3];
  int lane = threadIdx.x & 63, wid = threadIdx.x >> 6;
  int sc = s;
#pragma unroll
  for (int off = 1; off < 64; off <<= 1) {
    int t = __shfl_up(sc, off, 64);
    if (lane >= off) sc += t;
  }
  __shared__ int ws4[4];
  if (lane == 63) ws4[wid] = sc;
  __syncthreads();
  int wbase = 0;
  for (int w = 0; w < wid; w++) wbase += ws4[w];
  int p = part_excl[ty * 64 + blockIdx.x] + wbase + sc - s;
#pragma unroll
  for (int j = 0; j < 4; j++) {
    if (base + j < n) { rp[base + j] = p; cur[base + j] = p; }
    p += v[j];
  }
}

// ---------------------------------------------------------------------------
// GEMM body (device fn): operand-swapped MFMA; also computes es (scaled by
// LOG2E) and ed = x.vec for both dst halves (scaled), so the gather needs
// only scalar loads.
#define EBLK ((NE_N + 63) / 64)
#define PBLK ((NP_N + 63) / 64)
#define GEMM_BLK (EBLK + PBLK)
static __device__ __forceinline__ void gemm_body(
    int blk, const ushort* __restrict__ xe, const ushort* __restrict__ xp,
    const ushort* __restrict__ WbT, const float* __restrict__ att,
    const float* __restrict__ vec, int l, unsigned char* __restrict__ hsE0,
    unsigned char* __restrict__ hsE1, unsigned char* __restrict__ hsP3,
    unsigned char* __restrict__ hsP2, float* __restrict__ esE0,
    float* __restrict__ esE1, float* __restrict__ esP3,
    float* __restrict__ esP2, float* __restrict__ edEA,
    float* __restrict__ edEB, float* __restrict__ edPA,
    float* __restrict__ edPB) {
  const ushort* xb;
  const ushort *W0T, *W1T;
  const float *a0, *a1, *dv0, *dv1;
  unsigned char *hs0, *hs1;
  float *es0, *es1, *edA, *edB;
  int N;
  if (blk < EBLK) {
    xb = xe; N = NE_N;
    W0T = WbT + (size_t)(l * 4 + 0) * DIM * DIM;
    W1T = WbT + (size_t)(l * 4 + 1) * DIM * DIM;
    a0 = att + (l * 4 + 0) * DIM; a1 = att + (l * 4 + 1) * DIM;
    dv0 = vec + (l * 4 + 0) * DIM; dv1 = vec + (l * 4 + 3) * DIM;
    hs0 = hsE0; hs1 = hsE1; es0 = esE0; es1 = esE1;
    edA = edEA; edB = edEB;
  } else {
    blk -= EBLK; xb = xp; N = NP_N;
    W0T = WbT + (size_t)(l * 4 + 3) * DIM * DIM;
    W1T = WbT + (size_t)(l * 4 + 2) * DIM * DIM;
    a0 = att + (l * 4 + 3) * DIM; a1 = att + (l * 4 + 2) * DIM;
    dv0 = vec + (l * 4 + 1) * DIM; dv1 = vec + (l * 4 + 2) * DIM;
    hs0 = hsP3; hs1 = hsP2; es0 = esP3; es1 = esP2;
    edA = edPA; edB = edPB;
  }

  const int wave = threadIdx.x >> 6;
  const int lane = threadIdx.x & 63;
  const int m = lane & 15, quad = lane >> 4;
  const int row0 = blk * 64 + wave * 16;
  if (row0 >= N) return;
  int rowA = row0 + m;
  if (rowA >= N) rowA = N - 1;  // clamp loads; stores guarded

  f32x4 acc0[8], acc1[8];
#pragma unroll
  for (int f = 0; f < 8; f++) {
    acc0[f] = (f32x4){0.f, 0.f, 0.f, 0.f};
    acc1[f] = (f32x4){0.f, 0.f, 0.f, 0.f};
  }

  float edp0 = 0.f, edp1 = 0.f;
  const short8* xpr = (const short8*)(xb + (size_t)rowA * DIM + quad * 8);
#pragma unroll
  for (int k0 = 0; k0 < 4; k0++) {
    short8 xv = xpr[k0 * 4];  // x[rowA][k0*32 + quad*8 .. +7]
    // ed partials (fp32 vec, x in bf16)
    {
      int off = k0 * 32 + quad * 8;
      float4 vA0 = *(const float4*)&dv0[off];
      float4 vA1 = *(const float4*)&dv0[off + 4];
      float4 vB0 = *(const float4*)&dv1[off];
      float4 vB1 = *(const float4*)&dv1[off + 4];
      float x0 = bf2f(xv[0]), x1 = bf2f(xv[1]), x2 = bf2f(xv[2]),
            x3 = bf2f(xv[3]), x4 = bf2f(xv[4]), x5 = bf2f(xv[5]),
            x6 = bf2f(xv[6]), x7 = bf2f(xv[7]);
      edp0 += x0 * vA0.x + x1 * vA0.y + x2 * vA0.z + x3 * vA0.w +
              x4 * vA1.x + x5 * vA1.y + x6 * vA1.z + x7 * vA1.w;
      edp1 += x0 * vB0.x + x1 * vB0.y + x2 * vB0.z + x3 * vB0.w +
              x4 * vB1.x + x5 * vB1.y + x6 * vB1.z + x7 * vB1.w;
    }
#pragma unroll
    for (int f = 0; f < 8; f++) {
      size_t boff = (size_t)(f * 16 + m) * DIM + k0 * 32 + quad * 8;
      short8 w0 = *(const short8*)(W0T + boff);
      acc0[f] = __builtin_amdgcn_mfma_f32_16x16x32_bf16(w0, xv, acc0[f], 0, 0, 0);
      short8 w1 = *(const short8*)(W1T + boff);
      acc1[f] = __builtin_amdgcn_mfma_f32_16x16x32_bf16(w1, xv, acc1[f], 0, 0, 0);
    }
  }

  const int row = row0 + m;
  // ed: reduce over quad, store scaled by LOG2E
  edp0 += __shfl_xor(edp0, 16, 64);
  edp0 += __shfl_xor(edp0, 32, 64);
  edp1 += __shfl_xor(edp1, 16, 64);
  edp1 += __shfl_xor(edp1, 32, 64);
  if (quad == 0 && row < N) {
    edA[row] = edp0 * LOG2E;
    edB[row] = edp1 * LOG2E;
  }

#pragma unroll
  for (int set = 0; set < 2; set++) {
    f32x4* acc = set ? acc1 : acc0;
    const float* as = set ? a1 : a0;
    float* es = set ? es1 : es0;
    unsigned char* hs = set ? hs1 : hs0;

    // es: lane-local partial dot, reduce over quad, store scaled by LOG2E
    float esum = 0.f;
#pragma unroll
    for (int f = 0; f < 8; f++) {
      float4 av = *(const float4*)&as[f * 16 + quad * 4];
      esum += acc[f][0] * av.x + acc[f][1] * av.y + acc[f][2] * av.z +
              acc[f][3] * av.w;
    }
    esum += __shfl_xor(esum, 16, 64);
    esum += __shfl_xor(esum, 32, 64);
    if (quad == 0 && row < N) es[row] = esum * LOG2E;

    // hs fp8: pack 4 local cols into one dword, fully-active store
    if (row < N) {
#pragma unroll
      for (int f = 0; f < 8; f++) {
        int w = __builtin_amdgcn_cvt_pk_fp8_f32(acc[f][0], acc[f][1], 0, false);
        w = __builtin_amdgcn_cvt_pk_fp8_f32(acc[f][2], acc[f][3], w, true);
        *(unsigned*)&hs[(size_t)row * DIM + f * 16 + quad * 4] = (unsigned)w;
      }
    }
  }
}

// standalone gemm (layers 1,2)
__global__ __launch_bounds__(256) void gemm_k(
    const ushort* __restrict__ xe, const ushort* __restrict__ xp,
    const ushort* __restrict__ WbT, const float* __restrict__ att,
    const float* __restrict__ vec, int l, unsigned char* __restrict__ hsE0,
    unsigned char* __restrict__ hsE1, unsigned char* __restrict__ hsP3,
    unsigned char* __restrict__ hsP2, float* __restrict__ esE0,
    float* __restrict__ esE1, float* __restrict__ esP3,
    float* __restrict__ esP2, float* __restrict__ edEA,
    float* __restrict__ edEB, float* __restrict__ edPA,
    float* __restrict__ edPB) {
  gemm_body(blockIdx.x, xe, xp, WbT, att, vec, l, hsE0, hsE1, hsP3, hsP2,
            esE0, esE1, esP3, esP2, edEA, edEB, edPA, edPB);
}

// fused CSR-fill + layer-0 gemm (independent work, one dispatch)
__global__ __launch_bounds__(256) void fill_gemm0_k(
    const ushort* __restrict__ xe, const ushort* __restrict__ xp,
    const ushort* __restrict__ WbT, const float* __restrict__ att,
    const float* __restrict__ vec, unsigned char* __restrict__ hsE0,
    unsigned char* __restrict__ hsE1, unsigned char* __restrict__ hsP3,
    unsigned char* __restrict__ hsP2, float* __restrict__ esE0,
    float* __restrict__ esE1, float* __restrict__ esP3,
    float* __restrict__ esP2, float* __restrict__ edEA,
    float* __restrict__ edEB, float* __restrict__ edPA,
    float* __restrict__ edPB, const int* __restrict__ s0,
    const int* __restrict__ s1, const int* __restrict__ s2,
    const int* __restrict__ s3, const int* __restrict__ d0,
    const int* __restrict__ d1, const int* __restrict__ d2,
    const int* __restrict__ d3, int* __restrict__ u0, int* __restrict__ u1,
    int* __restrict__ u2, int* __restrict__ u3, ushort* __restrict__ o0,
    ushort* __restrict__ o1, ushort* __restrict__ o2,
    ushort* __restrict__ o3) {
  int blk = blockIdx.x;
  if (blk < GEMM_BLK) {
    gemm_body(blk, xe, xp, WbT, att, vec, 0, hsE0, hsE1, hsP3, hsP2, esE0,
              esE1, esP3, esP2, edEA, edEB, edPA, edPB);
  } else {
    int b = blk - GEMM_BLK;
    int ty = b / 782;
    int e = (b % 782) * 256 + threadIdx.x;
    if (e >= E_N) return;
    const int* src = ty == 0 ? s0 : ty == 1 ? s1 : ty == 2 ? s2 : s3;
    const int* dst = ty == 0 ? d0 : ty == 1 ? d1 : ty == 2 ? d2 : d3;
    int* cur = ty == 0 ? u0 : ty == 1 ? u1 : ty == 2 ? u2 : u3;
    ushort* out = ty == 0 ? o0 : ty == 1 ? o1 : ty == 2 ? o2 : o3;
    int pos = atomicAdd(&cur[dst[e]], 1);
    out[pos] = (ushort)src[e];
  }
}

// ---------------------------------------------------------------------------
// Combined dual-type gather. es/ed pre-scaled by LOG2E -> w = exp2(relu(.)).
// ed precomputed in gemm (scalar load here). Per-slot normalization with
// deferred slot-combine (one 16-bpermute combine at the end).
__global__ __launch_bounds__(256) void gat_gather_all(
    const int* __restrict__ rp0, const ushort* __restrict__ ss0,
    const int* __restrict__ rp1, const ushort* __restrict__ ss1,
    const int* __restrict__ rp2, const ushort* __restrict__ ss2,
    const int* __restrict__ rp3, const ushort* __restrict__ ss3,
    const float* __restrict__ esE0, const unsigned char* __restrict__ hsE0,
    const float* __restrict__ esE1, const unsigned char* __restrict__ hsE1,
    const float* __restrict__ esP3, const unsigned char* __restrict__ hsP3,
    const float* __restrict__ esP2, const unsigned char* __restrict__ hsP2,
    const float* __restrict__ edEA, const float* __restrict__ edEB,
    const float* __restrict__ edPA, const float* __restrict__ edPB,
    const float* __restrict__ bias, int l, ushort* __restrict__ outxe,
    ushort* __restrict__ outxp) {
  const int wid = (blockIdx.x * 256 + threadIdx.x) >> 6;
  const int lane = threadIdx.x & 63;
  const int slot = lane >> 4, sub = lane & 15;

  int node;
  const int *rpA, *rpB;
  const ushort *ssA, *ssB;
  const float *esA, *esB;
  const unsigned char *hsA, *hsB;
  float edvA, edvB;
  const float *b0, *b1;
  ushort* outb;
  if (wid < NE_N) {  // e-dst: ee (A) + pe (B)
    node = wid;
    rpA = rp0; ssA = ss0; esA = esE0; hsA = hsE0;
    rpB = rp3; ssB = ss3; esB = esP3; hsB = hsP3;
    edvA = edEA[node]; edvB = edEB[node];
    b0 = bias + (l * 4 + 0) * DIM; b1 = bias + (l * 4 + 3) * DIM;
    outb = outxe;
  } else if (wid < NE_N + NP_N) {  // p-dst: ep (A) + pp (B)
    node = wid - NE_N;
    rpA = rp1; ssA = ss1; esA = esE1; hsA = hsE1;
    rpB = rp2; ssB = ss2; esB = esP2; hsB = hsP2;
    edvA = edPA[node]; edvB = edPB[node];
    b0 = bias + (l * 4 + 1) * DIM; b1 = bias + (l * 4 + 2) * DIM;
    outb = outxp;
  } else {
    return;
  }

  float res[8];
#pragma unroll
  for (int j = 0; j < 8; j++) res[j] = 0.f;

#pragma unroll
  for (int half = 0; half < 2; half++) {
    const int* rp = half ? rpB : rpA;
    const ushort* ss = half ? ssB : ssA;
    const float* es = half ? esB : esA;
    const unsigned char* hs = half ? hsB : hsA;
    const float edv = half ? edvB : edvA;
    const int beg = rp[node], end = rp[node + 1];

    float acc[8];
#pragma unroll
    for (int j = 0; j < 8; j++) acc[j] = 0.f;
    float sw = 0.f;

    // single pass: w = exp2(relu(es'+ed')); acc += w*h; sw += w
    for (int e = beg + slot; e < end; e += 4) {
      int s = ss[e];
      float w = exp2f(fmaxf(es[s] + edv, 0.f));
      sw += w;
      uint2 h = *(const uint2*)&hs[(size_t)s * DIM + sub * 8];
      auto p01 = __builtin_amdgcn_cvt_pk_f32_fp8((int)h.x, false);
      auto p23 = __builtin_amdgcn_cvt_pk_f32_fp8((int)h.x, true);
      auto p45 = __builtin_amdgcn_cvt_pk_f32_fp8((int)h.y, false);
      auto p67 = __builtin_amdgcn_cvt_pk_f32_fp8((int)h.y, true);
      acc[0] += w * p01[0]; acc[1] += w * p01[1];
      acc[2] += w * p23[0]; acc[3] += w * p23[1];
      acc[4] += w * p45[0]; acc[5] += w * p45[1];
      acc[6] += w * p67[0]; acc[7] += w * p67[1];
    }

    // only sw needs cross-slot reduce now; acc combine deferred
    sw += __shfl_xor(sw, 16, 64);
    sw += __shfl_xor(sw, 32, 64);
    const float inv = 1.f / fmaxf(sw, 1e-16f);
#pragma unroll
    for (int j = 0; j < 8; j++) res[j] += acc[j] * inv;
  }

  // single slot-combine of normalized per-slot partials
#pragma unroll
  for (int j = 0; j < 8; j++) {
    res[j] += __shfl_xor(res[j], 16, 64);
    res[j] += __shfl_xor(res[j], 32, 64);
  }

  // lane stores dims d, d+1 where d = sub*8 + slot*2 (coalesced 256B row)
  const int d = sub * 8 + slot * 2;
  float2 bb0 = *(const float2*)&b0[d];
  float2 bb1 = *(const float2*)&b1[d];
  float v0 = res[slot * 2] + bb0.x + bb1.x;
  float v1 = res[slot * 2 + 1] + bb0.y + bb1.y;
  ushort2 o; o.x = f2bf(v0); o.y = f2bf(v1);
  *(ushort2*)&outb[(size_t)node * DIM + d] = o;
}

// ---------------------------------------------------------------------------
__global__ __launch_bounds__(256) void colsum_k(
    const ushort* __restrict__ xe, const ushort* __restrict__ xp,
    float* __restrict__ colsum) {
  int tid = blockIdx.x * 256 + threadIdx.x;
  const int stride = 256 * 256;  // multiple of 128 -> fixed column per thread
  float s = 0.f;
  for (int idx = tid; idx < NE_N * DIM; idx += stride) s += bf2f(xe[idx]);
  for (int idx = tid; idx < NP_N * DIM; idx += stride) s += bf2f(xp[idx]);
  __shared__ float ls[256];
  ls[threadIdx.x] = s;
  __syncthreads();
  if (threadIdx.x < 128)
    unsafeAtomicAdd(&colsum[threadIdx.x], ls[threadIdx.x] + ls[threadIdx.x + 128]);
}

// ---------------------------------------------------------------------------
__global__ void final_proj(const float* __restrict__ colsum,
                           const float* __restrict__ lin_W,
                           const float* __restrict__ lin_b,
                           float* __restrict__ out) {
  int j = threadIdx.x;
  if (j >= 2) return;
  float s = 0.f;
#pragma unroll 8
  for (int k = 0; k < DIM; k++) s += colsum[k] * lin_W[k * 2 + j];
  out[j] = s / (float)(NE_N + NP_N) + lin_b[j];
}

// ---------------------------------------------------------------------------
extern "C" void kernel_launch(void* const* d_in, const int* in_sizes, int n_in,
                              void* d_out, int out_size, void* d_ws,
                              size_t ws_size, hipStream_t stream) {
  const float* x_elem  = (const float*)d_in[0];
  const float* x_proc  = (const float*)d_in[1];
  const float* W_src   = (const float*)d_in[2];
  const float* W_dst   = (const float*)d_in[3];
  const float* att_src = (const float*)d_in[4];
  const float* att_dst = (const float*)d_in[5];
  const float* bias    = (const float*)d_in[6];
  const float* lin_W   = (const float*)d_in[7];
  const float* lin_b   = (const float*)d_in[8];
  const int* esrc[4] = {(const int*)d_in[9],  (const int*)d_in[11],
                        (const int*)d_in[13], (const int*)d_in[15]};
  const int* edst[4] = {(const int*)d_in[10], (const int*)d_in[12],
                        (const int*)d_in[14], (const int*)d_in[16]};

  // ---- workspace carve-up (16B-aligned chunks) ----
  char* p = (char*)d_ws;
  ushort* xe_bf[2]; ushort* xp_bf[2];
  xe_bf[0] = (ushort*)p; p += (size_t)NE_N * DIM * 2;
  xe_bf[1] = (ushort*)p; p += (size_t)NE_N * DIM * 2;
  xp_bf[0] = (ushort*)p; p += (size_t)NP_N * DIM * 2;
  xp_bf[1] = (ushort*)p; p += (size_t)NP_N * DIM * 2;
  unsigned char* hsE0 = (unsigned char*)p; p += (size_t)NE_N * DIM;  // W[l,0]
  unsigned char* hsE1 = (unsigned char*)p; p += (size_t)NE_N * DIM;  // W[l,1]
  unsigned char* hsP3 = (unsigned char*)p; p += (size_t)NP_N * DIM;  // W[l,3]
  unsigned char* hsP2 = (unsigned char*)p; p += (size_t)NP_N * DIM;  // W[l,2]
  ushort* WbT = (ushort*)p; p += (size_t)12 * DIM * DIM * 2;
  float* esE0 = (float*)p; p += (size_t)NE_N * 4;
  float* esE1 = (float*)p; p += (size_t)NE_N * 4;
  float* esP3 = (float*)p; p += (size_t)NP_N * 4;
  float* esP2 = (float*)p; p += (size_t)NP_N * 4;
  float* edEA = (float*)p; p += (size_t)NE_N * 4;
  float* edEB = (float*)p; p += (size_t)NE_N * 4;
  float* edPA = (float*)p; p += (size_t)NP_N * 4;
  float* edPB = (float*)p; p += (size_t)NP_N * 4;
  float* vec = (float*)p; p += 12 * DIM * 4;
  float* part = (float*)p ? (float*)p : nullptr;  // placeholder keep layout
  int* parti = (int*)p; p += 4 * 64 * 4;
  int* part_excl = (int*)p; p += 4 * 64 * 4;
  // cursor[4] + csum contiguous -> single memset
  int* cursor[4];
  for (int t = 0; t < 4; t++) { cursor[t] = (int*)p; p += (NE_N + 4) * 4; }
  float* csum = (float*)p; p += DIM * 4;
  int* rp[4];
  for (int t = 0; t < 4; t++) { rp[t] = (int*)p; p += (NE_N + 4) * 4; }
  ushort* ssrc[4];
  for (int t = 0; t < 4; t++) { ssrc[t] = (ushort*)p; p += (size_t)E_N * 2; }
  (void)part;

  // ---- zero cursors + csum in one memset ----
  hipMemsetAsync(cursor[0], 0, 4 * (NE_N + 4) * sizeof(int) + DIM * sizeof(float),
                 stream);

  // ---- fused setup: conv_w | conv_x | vec | hist ----
  setup_fused<<<SU_CW + SU_CX + SU_V + SU_H, 256, 0, stream>>>(
      W_src, x_elem, x_proc, W_dst, att_dst, WbT, xe_bf[0], xp_bf[0], vec,
      edst[0], edst[1], edst[2], edst[3], cursor[0], cursor[1], cursor[2],
      cursor[3]);

  scanA_k<<<dim3(49, 4), 256, 0, stream>>>(cursor[0], cursor[1], cursor[2],
                                           cursor[3], parti);
  scanB_k<<<1, 256, 0, stream>>>(parti, part_excl, rp[0], rp[1], rp[2], rp[3]);
  scanC_k<<<dim3(49, 4), 256, 0, stream>>>(cursor[0], cursor[1], cursor[2],
                                           cursor[3], rp[0], rp[1], rp[2],
                                           rp[3], cursor[0], cursor[1],
                                           cursor[2], cursor[3], part_excl);

  // ---- fill CSR + layer-0 gemm fused ----
  fill_gemm0_k<<<GEMM_BLK + 3128, 256, 0, stream>>>(
      xe_bf[0], xp_bf[0], WbT, att_src, vec, hsE0, hsE1, hsP3, hsP2, esE0,
      esE1, esP3, esP2, edEA, edEB, edPA, edPB, esrc[0], esrc[1], esrc[2],
      esrc[3], edst[0], edst[1], edst[2], edst[3], cursor[0], cursor[1],
      cursor[2], cursor[3], ssrc[0], ssrc[1], ssrc[2], ssrc[3]);

  // ---- layers ----
  int c = 0;
  for (int l = 0; l < 3; l++) {
    if (l > 0) {
      gemm_k<<<GEMM_BLK, 256, 0, stream>>>(
          xe_bf[c], xp_bf[c], WbT, att_src, vec, l, hsE0, hsE1, hsP3, hsP2,
          esE0, esE1, esP3, esP2, edEA, edEB, edPA, edPB);
    }
    gat_gather_all<<<(NE_N + NP_N) / 4, 256, 0, stream>>>(
        rp[0], ssrc[0], rp[1], ssrc[1], rp[2], ssrc[2], rp[3], ssrc[3], esE0,
        hsE0, esE1, hsE1, esP3, hsP3, esP2, hsP2, edEA, edEB, edPA, edPB,
        bias, l, xe_bf[1 - c], xp_bf[1 - c]);
    c = 1 - c;
  }

  colsum_k<<<256, 256, 0, stream>>>(xe_bf[c], xp_bf[c], csum);
  final_proj<<<1, 64, 0, stream>>>(csum, lin_W, lin_b, (float*)d_out);
}